// Round 15
// baseline (2598.492 us; speedup 1.0000x reference)
//
#include <hip/hip_runtime.h>

typedef unsigned int u32;
typedef unsigned long long u64;

#define NPTS  1024
#define DIMD  512
#define KCL   64
#define KMIT  10

// ---- workspace layout (element offsets, all 4-byte elems) ----
constexpr size_t O_CTG  = 0;                        // [64 runs][512 d][64 c]
constexpr size_t O_SUMS = O_CTG  + 64ull*512*64;    // [64][64 c][512 d] (reused: PS0, then CS)
constexpr size_t O_CNT  = O_SUMS + 64ull*64*512;    // [64][64] int
constexpr size_t O_SQC  = O_CNT  + 64ull*64;        // [64][64]
constexpr size_t O_SQP  = O_SQC  + 64ull*64;        // [64][1024]
constexpr size_t O_ASG  = O_SQP  + 64ull*1024;      // [64][1024] int (dead; kept for layout)
constexpr size_t O_CTN  = O_ASG  + 64ull*1024;      // [8 n][256 c][512 d]
constexpr size_t O_Y    = O_CTN  + 8ull*256*512;    // [8][4][4][64] int
constexpr size_t O_CNT2 = O_Y    + 8ull*4*4*64;     // [8][256] int
constexpr size_t O_BM   = O_CNT2 + 8ull*256;        // [8][256 c][512 d]
constexpr size_t O_G    = O_BM   + 8ull*256*512;    // [8][256][256]
constexpr size_t O_LT   = O_G    + 8ull*256*256;    // [8][256][256]  LT[a][b]=L[b][a]
constexpr size_t O_YB   = O_LT   + 8ull*256*256;    // [8][256][512] (reused: W/WT)
constexpr size_t O_ZB   = O_YB   + 8ull*256*512;    // [8][256][512]
constexpr size_t O_PTST = O_ZB   + 8ull*256*512;    // [64][1024 p][512 d]

// partial sums for kmeans (loop-phase only).
constexpr size_t O_PS0 = O_SUMS;                    // [64][64 c][512 d]
constexpr size_t O_PS1 = O_CTN;                     // [64][64 c][512 d]
static_assert(O_PS1 + 64ull*64*512 <= O_G, "PS1 overlay must fit before O_G");

// per-block argmin candidates (loop-phase only): overlay O_G (post-loop buffer).
constexpr size_t O_BEST = O_G;

// post-loop overlays:
constexpr size_t O_CS = O_SUMS;                     // [8 n][4 i][64 k][512 d] source centers rows
constexpr size_t O_W  = O_YB;                       // [8][4][64 r][64 k]  W = inv(L_ii)
constexpr size_t O_WT = O_YB + 8ull*4*64*64;        // [8][4][64 k][64 r]  W^T

__device__ __forceinline__ const float* run_base(const float* s, const float* t, int run){
    const float* b = (run < 32) ? s : t;
    return b + (size_t)(run & 31) * (DIMD * NPTS);
}
// monotonic pack of (d2, idx): min picks smallest d2, ties -> smallest idx (matches jnp.argmin)
__device__ __forceinline__ u64 dpack(float d2, int c){
    u32 u = __float_as_uint(d2);
    u = (u & 0x80000000u) ? ~u : (u | 0x80000000u);
    return ((u64)u << 32) | (u32)c;
}
__device__ __forceinline__ float rdlane(float v, int l){
    return __uint_as_float(__builtin_amdgcn_readlane(__float_as_uint(v), l));
}

// ---- init: sqp (per-point |p|^2), initial centers (first 64 pts), sqc, zero cnt ----
__global__ __launch_bounds__(256) void k_init(const float* __restrict__ src, const float* __restrict__ tgt,
                                              float* __restrict__ ws){
    int bx = blockIdx.x; int run = bx >> 2, q = bx & 3;
    int tid = threadIdx.x;
    const float* base = run_base(src, tgt, run);
    int p = q*256 + tid;
    float acc = 0.f;
    for (int d = 0; d < DIMD; ++d){
        float v = base[(size_t)d*NPTS + p];
        acc = fmaf(v, v, acc);
    }
    ws[O_SQP + run*NPTS + p] = acc;
    if (q == 0){
        if (tid < KCL) ws[O_SQC + run*KCL + tid] = acc;
        if (tid < KCL) ((int*)(ws + O_CNT))[run*KCL + tid] = 0;
        for (int idx = tid; idx < DIMD*KCL; idx += 256){
            int d = idx >> 6, c = idx & 63;
            ws[O_CTG + (size_t)run*DIMD*KCL + idx] = base[(size_t)d*NPTS + c];
        }
    }
}

// ---- build transposed points copy [run][p][d] for deterministic sums ----
__global__ __launch_bounds__(256) void k_ptsT(const float* __restrict__ src, const float* __restrict__ tgt,
                                              float* __restrict__ ws){
    int bx = blockIdx.x; int dt = bx & 7, pt = (bx >> 3) & 15, run = bx >> 7;
    int tid = threadIdx.x, lane = tid & 63, r4 = tid >> 6;
    const float* base = run_base(src, tgt, run);
    __shared__ float t[64*65];
    for (int pass = 0; pass < 16; ++pass){
        int r = pass*4 + r4;
        t[r*65 + lane] = base[(size_t)(dt*64 + r)*NPTS + pt*64 + lane];
    }
    __syncthreads();
    for (int pass = 0; pass < 16; ++pass){
        int p = pass*4 + r4;
        ws[O_PTST + ((size_t)run*NPTS + pt*64 + p)*DIMD + dt*64 + lane] = t[lane*65 + p];
    }
}

// ---- kmeans assignment, center-split: 1024 blocks (4/CU, 4 waves/SIMD) ----
// 16-dim prefetch batches (32 batches total = 512 dims).
__global__ __launch_bounds__(256, 4) void k_assign(const float* __restrict__ src, const float* __restrict__ tgt,
                                                   const float* __restrict__ ctr, const float* __restrict__ sqc,
                                                   const float* __restrict__ sqp,
                                                   u64* __restrict__ bestg){
    int bxx = blockIdx.x;                    // 0..1023
    int cb  = (bxx >> 3) & 1;
    int w   = ((bxx >> 4) << 3) | (bxx & 7); // 0..511
    int run = w >> 3, qt = w & 7;
    int tid = threadIdx.x, lane = tid & 63;
    int g = __builtin_amdgcn_readfirstlane(tid >> 6);
    int c0 = cb*32 + g*8;                    // this wave's 8 centers
    const float* base = run_base(src, tgt, run);
    const float* cg = ctr + (size_t)run*DIMD*KCL + c0;
    int p0 = qt*128 + 2*lane;                // points p0, p0+1
    float acc[2][8] = {};
    __shared__ u64 red[4][128];

#define LOADP(P, B) { \
    _Pragma("unroll") \
    for (int u = 0; u < 16; ++u) \
        P[u] = *(const float2*)&base[(size_t)((B)*16 + u)*NPTS + p0]; }

#define COMPUTE(P, B) { \
    _Pragma("unroll") \
    for (int u = 0; u < 16; ++u){ \
        const float4* cp = (const float4*)(cg + (size_t)((B)*16 + u)*KCL); \
        float4 c0v = cp[0], c1v = cp[1]; \
        float cv[8] = {c0v.x,c0v.y,c0v.z,c0v.w, c1v.x,c1v.y,c1v.z,c1v.w}; \
        _Pragma("unroll") \
        for (int cl = 0; cl < 8; ++cl){ \
            acc[0][cl] = fmaf(P[u].x, cv[cl], acc[0][cl]); \
            acc[1][cl] = fmaf(P[u].y, cv[cl], acc[1][cl]); \
        } \
    } }

    float2 pa[16], pb[16];
    LOADP(pa, 0);
    for (int b = 0; b < 32; b += 2){
        if (b + 1 < 32) LOADP(pb, b + 1);
        COMPUTE(pa, b);
        if (b + 2 < 32) LOADP(pa, b + 2);
        COMPUTE(pb, b + 1);
    }
#undef LOADP
#undef COMPUTE

    const float* sqcg = sqc + run*KCL + c0;
    float sq[8];
    #pragma unroll
    for (int q = 0; q < 8; ++q) sq[q] = sqcg[q];
    float2 sq2 = *(const float2*)&sqp[run*NPTS + p0];
    #pragma unroll
    for (int s = 0; s < 2; ++s){
        float sqpv = s ? sq2.y : sq2.x;
        u64 best = dpack(sqpv + sq[0] - 2.f*acc[s][0], c0);
        #pragma unroll
        for (int cl = 1; cl < 8; ++cl){
            u64 k2 = dpack(sqpv + sq[cl] - 2.f*acc[s][cl], c0 + cl);
            best = (k2 < best) ? k2 : best;
        }
        red[g][2*lane + s] = best;
    }
    __syncthreads();
    if (tid < 128){
        u64 b = red[0][tid];
        #pragma unroll
        for (int g2 = 1; g2 < 4; ++g2){ u64 k2 = red[g2][tid]; b = (k2 < b) ? k2 : b; }
        bestg[(((size_t)(run*8 + qt)*128 + tid) << 1) + cb] = b;
    }
}

// ---- kmeans partial sums + inline argmin-combine ----
__global__ __launch_bounds__(256) void k_sums(float* __restrict__ ws){
    int bx = blockIdx.x; int pg = bx & 1, dh = (bx >> 1) & 1, run = bx >> 2;
    int tid = threadIdx.x;
    __shared__ float sm[KCL*256];
    __shared__ int a[512];
    const u64* bestg = (const u64*)(ws + O_BEST);
    int* cnt = (int*)(ws + O_CNT);
    for (int idx = tid; idx < 512; idx += 256){
        int p = pg*512 + idx;
        int qt = p >> 7, t = p & 127;
        const u64* bp = bestg + (((size_t)(run*8 + qt)*128 + t) << 1);
        u64 x = bp[0], y = bp[1];
        u64 m = (y < x) ? y : x;
        int c = (int)(m & 0xffffffffu);
        a[idx] = c;
        if (dh == 0) atomicAdd(&cnt[run*KCL + c], 1);
    }
    for (int idx = tid; idx < KCL*256; idx += 256) sm[idx] = 0.f;
    __syncthreads();
    const float* pT = ws + O_PTST + ((size_t)run*NPTS + pg*512)*DIMD + dh*256 + tid;
    for (int p = 0; p < 512; p += 4){
        float v0 = pT[(size_t)(p+0)*DIMD], v1 = pT[(size_t)(p+1)*DIMD];
        float v2 = pT[(size_t)(p+2)*DIMD], v3 = pT[(size_t)(p+3)*DIMD];
        sm[a[p+0]*256 + tid] += v0;
        sm[a[p+1]*256 + tid] += v1;
        sm[a[p+2]*256 + tid] += v2;
        sm[a[p+3]*256 + tid] += v3;
    }
    __syncthreads();
    size_t psx = pg ? O_PS1 : O_PS0;
    for (int c = 0; c < KCL; ++c)
        ws[psx + ((size_t)run*KCL + c)*DIMD + dh*256 + tid] = sm[c*256 + tid];
}

// ---- kmeans center update + sqc + zero cnt (deterministic: ps0+ps1) ----
__global__ __launch_bounds__(256) void k_newc(float* __restrict__ ws){
    int run = blockIdx.x, tid = threadIdx.x;
    __shared__ float sm2[KCL*65];
    __shared__ int cl[KCL];
    int* cnt = (int*)(ws + O_CNT);
    if (tid < KCL) cl[tid] = cnt[run*KCL + tid];
    __syncthreads();
    if (tid < KCL) cnt[run*KCL + tid] = 0;
    float sqa = 0.f;
    for (int dc = 0; dc < 8; ++dc){
        for (int idx = tid; idx < KCL*64; idx += 256){
            int c = idx >> 6, dl = idx & 63;
            size_t o = ((size_t)run*KCL + c)*DIMD + dc*64 + dl;
            sm2[c*65 + dl] = ws[O_PS0 + o] + ws[O_PS1 + o];
        }
        __syncthreads();
        for (int idx = tid; idx < KCL*64; idx += 256){
            int dl = idx >> 6, c = idx & 63, d = dc*64 + dl;
            size_t gi = O_CTG + (size_t)run*DIMD*KCL + d*KCL + c;
            float old = ws[gi];
            int cc = cl[c];
            float nv = (cc > 0) ? sm2[c*65 + dl] / (float)cc : old;
            ws[gi] = nv;
            sm2[c*65 + dl] = nv;
        }
        __syncthreads();
        if (tid < KCL){
            for (int dl = 0; dl < 64; ++dl){ float v = sm2[tid*65 + dl]; sqa = fmaf(v, v, sqa); }
        }
        __syncthreads();
    }
    if (tid < KCL) ws[O_SQC + run*KCL + tid] = sqa;
}

// ---- regroup centers to row-major: target -> CTN [n][256c][512d]; source -> CS [n][4i][64k][512d] ----
__global__ __launch_bounds__(256) void k_ctn(float* __restrict__ ws){
    int bx = blockIdx.x; int dc = bx & 7, jj = (bx >> 3) & 3, n = (bx >> 5) & 7, st = bx >> 8;
    int run = st ? (jj*8 + n) : (32 + jj*8 + n);
    int tid = threadIdx.x, lane = tid & 63, r4 = tid >> 6;
    __shared__ float t[64*65];
    for (int pass = 0; pass < 16; ++pass){
        int r = pass*4 + r4;
        t[r*65 + lane] = ws[O_CTG + (size_t)run*DIMD*KCL + (dc*64 + r)*KCL + lane];
    }
    __syncthreads();
    size_t dstbase = st ? (O_CS  + ((size_t)(n*4 + jj)*64)*DIMD)
                        : (O_CTN + ((size_t)n*256 + jj*64)*DIMD);
    for (int pass = 0; pass < 16; ++pass){
        int l = pass*4 + r4;
        ws[dstbase + (size_t)l*DIMD + dc*64 + lane] = t[lane*65 + l];
    }
}

// ---- source->target center matching ----
__global__ __launch_bounds__(256) void k_map(float* __restrict__ ws){
    int bx = blockIdx.x; int j = bx & 3, i = (bx >> 2) & 3, n = bx >> 4;
    int run_s = i*8 + n, run_t = 32 + j*8 + n;
    int tid = threadIdx.x, lane = tid & 63;
    int g = __builtin_amdgcn_readfirstlane(tid >> 6);
    const float* cgs = ws + O_CTG + (size_t)run_s*DIMD*KCL + lane;
    const float* cgt = ws + O_CTG + (size_t)run_t*DIMD*KCL + g*16;
    float acc[16] = {};
    for (int d = 0; d < DIMD; ++d){
        float csv = cgs[d*KCL];
        const float4* cp = (const float4*)(cgt + d*KCL);
        float4 c0=cp[0], c1=cp[1], c2=cp[2], c3=cp[3];
        float cv[16] = {c0.x,c0.y,c0.z,c0.w, c1.x,c1.y,c1.z,c1.w,
                        c2.x,c2.y,c2.z,c2.w, c3.x,c3.y,c3.z,c3.w};
        #pragma unroll
        for (int cl = 0; cl < 16; ++cl) acc[cl] = fmaf(csv, cv[cl], acc[cl]);
    }
    float sqs = ws[O_SQC + run_s*KCL + lane];
    const float* sqtp = ws + O_SQC + run_t*KCL + g*16;
    u64 best = dpack(sqs + sqtp[0] - 2.f*acc[0], g*16);
    #pragma unroll
    for (int cl = 1; cl < 16; ++cl){
        u64 k2 = dpack(sqs + sqtp[cl] - 2.f*acc[cl], g*16 + cl);
        best = (k2 < best) ? k2 : best;
    }
    __shared__ u64 red[4][64];
    red[g][lane] = best;
    __syncthreads();
    if (tid < 64){
        u64 b = red[0][tid];
        #pragma unroll
        for (int g2 = 1; g2 < 4; ++g2){ u64 k2 = red[g2][tid]; b = (k2 < b) ? k2 : b; }
        int l = (int)(b & 0xffffffffu);
        int* yv   = (int*)(ws + O_Y);
        int* cnt2 = (int*)(ws + O_CNT2);
        yv[((n*4 + i)*4 + j)*64 + tid] = l;
        atomicAdd(&cnt2[n*256 + j*64 + l], 1);
    }
}

// ---- B matrix: serial gather-accumulate over 256 sources, coalesced rows, no atomics ----
__global__ __launch_bounds__(256) void k_bmat(float* __restrict__ ws){
    int bx = blockIdx.x; int dh = bx & 1, j = (bx >> 1) & 3, n = bx >> 3;
    int tid = threadIdx.x;
    __shared__ float Bacc[KCL*256];   // 64 KB
    __shared__ int yl[256];
    __shared__ int c2[KCL];
    const int* yv   = (const int*)(ws + O_Y);
    const int* cnt2 = (const int*)(ws + O_CNT2);
    { int i = tid >> 6, k = tid & 63; yl[tid] = yv[((n*4 + i)*4 + j)*64 + k]; }
    if (tid < KCL) c2[tid] = cnt2[n*256 + j*64 + tid];
    for (int idx = tid; idx < KCL*256; idx += 256) Bacc[idx] = 0.f;
    __syncthreads();
    const float* cs = ws + O_CS + (size_t)(n*4)*64*DIMD + dh*256 + tid;
    #pragma unroll 4
    for (int s = 0; s < 256; ++s){
        int l = yl[s];
        float v = cs[(size_t)s*DIMD];
        Bacc[l*256 + tid] += v;
    }
    __syncthreads();
    for (int l = 0; l < KCL; ++l){
        int cc = c2[l]; if (cc < 1) cc = 1;
        ws[O_BM + ((size_t)n*256 + j*64 + l)*DIMD + dh*256 + tid] = Bacc[l*256 + tid] / (float)cc;
    }
}

// ---- masked Gram of target centers (identity on unused slots) ----
__global__ __launch_bounds__(256) void k_gram(float* __restrict__ ws){
    int bx = blockIdx.x; int cc = bx & 7, n = bx >> 3;
    int tid = threadIdx.x, llane = tid & 63, jlane = tid >> 6;
    int run_t = 32 + jlane*8 + n;
    const float* bbase = ws + O_CTG + (size_t)run_t*DIMD*KCL + llane;
    const float* arow  = ws + O_CTN + (size_t)(n*256 + cc*32)*DIMD;
    float acc[32] = {};
    for (int d = 0; d < DIMD; d += 4){
        float bv0 = bbase[(d+0)*KCL], bv1 = bbase[(d+1)*KCL];
        float bv2 = bbase[(d+2)*KCL], bv3 = bbase[(d+3)*KCL];
        #pragma unroll
        for (int c = 0; c < 32; ++c){
            const float4 av = *(const float4*)&arow[c*DIMD + d];
            acc[c] = fmaf(av.x, bv0, acc[c]);
            acc[c] = fmaf(av.y, bv1, acc[c]);
            acc[c] = fmaf(av.z, bv2, acc[c]);
            acc[c] = fmaf(av.w, bv3, acc[c]);
        }
    }
    const int* cnt2 = (const int*)(ws + O_CNT2);
    bool used_cp = cnt2[n*256 + tid] > 0;
    float* Gp = ws + O_G + (size_t)n*65536;
    #pragma unroll
    for (int c = 0; c < 32; ++c){
        int cg = cc*32 + c;
        bool used_c = cnt2[n*256 + cg] > 0;
        float v = (used_c && used_cp) ? acc[c] : ((cg == tid) ? 1.f : 0.f);
        Gp[(size_t)cg*256 + tid] = v;
    }
}

// ---- Cholesky panel: register-lockstep fused diag factor + panel solve (one kb) ----
__global__ __launch_bounds__(256, 1) void k_cholp(float* __restrict__ ws, int kb){
    int n = blockIdx.x, tid = threadIdx.x;
    int lane = tid & 63, wv = tid >> 6;
    float* Gn  = ws + O_G  + (size_t)n*65536;
    float* LTn = ws + O_LT + (size_t)n*65536;
    int c0 = kb*64, r1 = c0 + 64, rem = 256 - r1;

    float dreg[64];
    {
        const float* grow = Gn + (size_t)(c0+lane)*256 + c0;
        #pragma unroll
        for (int j4 = 0; j4 < 16; ++j4){
            float4 v = *(const float4*)&grow[j4*4];
            dreg[j4*4+0]=v.x; dreg[j4*4+1]=v.y; dreg[j4*4+2]=v.z; dreg[j4*4+3]=v.w;
        }
    }
    float preg[64];
    int prow = (wv-1)*64 + lane;
    bool pact = (wv >= 1) && (prow < rem);
    {
        const float* growp = Gn + (size_t)(r1+prow)*256 + c0;
        #pragma unroll
        for (int j4 = 0; j4 < 16; ++j4){
            if (pact){
                float4 v = *(const float4*)&growp[j4*4];
                preg[j4*4+0]=v.x; preg[j4*4+1]=v.y; preg[j4*4+2]=v.z; preg[j4*4+3]=v.w;
            } else {
                preg[j4*4+0]=0.f; preg[j4*4+1]=0.f; preg[j4*4+2]=0.f; preg[j4*4+3]=0.f;
            }
        }
    }
    #pragma unroll
    for (int k = 0; k < 64; ++k){
        float dkk = sqrtf(fmaxf(rdlane(dreg[k], k), 1e-30f));
        float inv = 1.f / dkk;
        dreg[k] = (lane == k) ? dkk : dreg[k]*inv;
        preg[k] *= inv;
        #pragma unroll
        for (int j = k+1; j < 64; ++j){
            float s = rdlane(dreg[k], j);
            dreg[j] = fmaf(-dreg[k], s, dreg[j]);
            preg[j] = fmaf(-preg[k], s, preg[j]);
        }
    }
    if (wv == 0){
        float* grow = Gn + (size_t)(c0+lane)*256 + c0;
        #pragma unroll
        for (int j4 = 0; j4 < 16; ++j4){
            float4 v; v.x=dreg[j4*4+0]; v.y=dreg[j4*4+1]; v.z=dreg[j4*4+2]; v.w=dreg[j4*4+3];
            *(float4*)&grow[j4*4] = v;
        }
    }
    if (pact){
        float* growp = Gn + (size_t)(r1+prow)*256 + c0;
        #pragma unroll
        for (int j4 = 0; j4 < 16; ++j4){
            float4 v; v.x=preg[j4*4+0]; v.y=preg[j4*4+1]; v.z=preg[j4*4+2]; v.w=preg[j4*4+3];
            *(float4*)&growp[j4*4] = v;
        }
        float* ltp = LTn + (size_t)c0*256 + r1 + prow;
        #pragma unroll
        for (int j = 0; j < 64; ++j) ltp[(size_t)j*256] = preg[j];
    }
}

// ---- trailing update for panel kb, wide-parallel: C -= Lp * Lp^T (lower 4x4 tiles) ----
__global__ __launch_bounds__(256) void k_trail(float* __restrict__ ws, int kb){
    int n = blockIdx.y;
    int c0 = kb*64, r1 = c0 + 64, rem = 256 - r1;
    int nt4 = rem >> 2;
    int ntiles = nt4*(nt4+1)/2;
    float* Gn = ws + O_G + (size_t)n*65536;
    for (int t = blockIdx.x*256 + threadIdx.x; t < ntiles; t += gridDim.x*256){
        int ti = (int)((sqrtf(8.f*(float)t + 1.f) - 1.f) * 0.5f);
        while ((ti+1)*(ti+2)/2 <= t) ++ti;
        while (ti*(ti+1)/2 > t) --ti;
        int tj = t - ti*(ti+1)/2;
        int i0 = ti*4, j0 = tj*4;
        const float* Li = Gn + (size_t)(r1+i0)*256 + c0;
        const float* Lj = Gn + (size_t)(r1+j0)*256 + c0;
        float acc[4][4] = {};
        for (int k = 0; k < 64; k += 4){
            float4 ar4[4], br4[4];
            #pragma unroll
            for (int r = 0; r < 4; ++r) ar4[r] = *(const float4*)&Li[(size_t)r*256 + k];
            #pragma unroll
            for (int s = 0; s < 4; ++s) br4[s] = *(const float4*)&Lj[(size_t)s*256 + k];
            #pragma unroll
            for (int q = 0; q < 4; ++q){
                float aq[4] = { q==0?ar4[0].x:q==1?ar4[0].y:q==2?ar4[0].z:ar4[0].w,
                                q==0?ar4[1].x:q==1?ar4[1].y:q==2?ar4[1].z:ar4[1].w,
                                q==0?ar4[2].x:q==1?ar4[2].y:q==2?ar4[2].z:ar4[2].w,
                                q==0?ar4[3].x:q==1?ar4[3].y:q==2?ar4[3].z:ar4[3].w };
                float bq[4] = { q==0?br4[0].x:q==1?br4[0].y:q==2?br4[0].z:br4[0].w,
                                q==0?br4[1].x:q==1?br4[1].y:q==2?br4[1].z:br4[1].w,
                                q==0?br4[2].x:q==1?br4[2].y:q==2?br4[2].z:br4[2].w,
                                q==0?br4[3].x:q==1?br4[3].y:q==2?br4[3].z:br4[3].w };
                #pragma unroll
                for (int r = 0; r < 4; ++r)
                    #pragma unroll
                    for (int s = 0; s < 4; ++s)
                        acc[r][s] = fmaf(aq[r], bq[s], acc[r][s]);
            }
        }
        #pragma unroll
        for (int r = 0; r < 4; ++r){
            float* grow = Gn + (size_t)(r1+i0+r)*256 + r1 + j0;
            #pragma unroll
            for (int s = 0; s < 4; ++s) grow[s] -= acc[r][s];
        }
    }
}

// ---- diag-block inverses: W_i = inv(L_ii), column-parallel per lane ----
__global__ __launch_bounds__(256, 1) void k_dinv(float* __restrict__ ws){
    int n = blockIdx.x, tid = threadIdx.x;
    int lane = tid & 63, kb = tid >> 6;
    const float* Gn = ws + O_G + (size_t)n*65536;
    __shared__ __align__(16) float DlT[4][64*65];   // DlT[kb][k*65+i] = L[i][k]
    for (int idx = lane; idx < 1024; idx += 64){
        int r = idx >> 4, c4 = idx & 15;
        float4 v = *(const float4*)&Gn[(size_t)(kb*64 + r)*256 + kb*64 + c4*4];
        DlT[kb][(c4*4+0)*65 + r] = v.x;
        DlT[kb][(c4*4+1)*65 + r] = v.y;
        DlT[kb][(c4*4+2)*65 + r] = v.z;
        DlT[kb][(c4*4+3)*65 + r] = v.w;
    }
    __syncthreads();
    float x[64];
    #pragma unroll
    for (int i = 0; i < 64; ++i) x[i] = (i == lane) ? 1.f : 0.f;
    const float* Dk = DlT[kb];
    #pragma unroll
    for (int k = 0; k < 64; ++k){
        float invd = 1.f / Dk[k*65 + k];
        x[k] *= invd;
        #pragma unroll
        for (int i = k+1; i < 64; ++i)
            x[i] = fmaf(-Dk[k*65 + i], x[k], x[i]);
    }
    float* Wg  = ws + O_W  + ((size_t)n*4 + kb)*4096;
    float* WTg = ws + O_WT + ((size_t)n*4 + kb)*4096;
    #pragma unroll
    for (int r = 0; r < 64; ++r) Wg[r*64 + lane] = x[r];
    #pragma unroll
    for (int r4 = 0; r4 < 16; ++r4){
        float4 v; v.x=x[r4*4+0]; v.y=x[r4*4+1]; v.z=x[r4*4+2]; v.w=x[r4*4+3];
        *(float4*)&WTg[lane*64 + r4*4] = v;
    }
}

// ---- triangular solves as block GEMMs: G Z = Ct via L Y = Ct; L^T Z = Y ----
__global__ __launch_bounds__(256, 1) void k_solve(float* __restrict__ ws){
    int n = blockIdx.x, cg = blockIdx.y;
    int tid = threadIdx.x;
    int tx = tid & 15, ty = tid >> 4;
    const float* Gn  = ws + O_G  + (size_t)n*65536;
    const float* LTn = ws + O_LT + (size_t)n*65536;
    const float* Ct  = ws + O_CTN + (size_t)n*256*DIMD + (size_t)cg*64;
    const float* Wg  = ws + O_W  + (size_t)n*4*4096;
    const float* WTg = ws + O_WT + (size_t)n*4*4096;
    float* Zb = ws + O_ZB + (size_t)n*256*DIMD + (size_t)cg*64;

    __shared__ __align__(16) float YL[4][64*65];
    __shared__ __align__(16) float At[64*65];
    __shared__ __align__(16) float RL[64*65];

    float acc[4][4];
    for (int bi = 0; bi < 4; ++bi){
        #pragma unroll
        for (int a = 0; a < 4; ++a){
            float4 v = *(const float4*)&Ct[(size_t)(bi*64 + ty*4 + a)*DIMD + tx*4];
            acc[a][0]=v.x; acc[a][1]=v.y; acc[a][2]=v.z; acc[a][3]=v.w;
        }
        for (int j = 0; j < bi; ++j){
            __syncthreads();
            for (int idx = tid; idx < 1024; idx += 256){
                int k = idx >> 4, r4 = idx & 15;
                float4 v = *(const float4*)&LTn[(size_t)(j*64 + k)*256 + bi*64 + r4*4];
                *(float4*)&At[k*65 + r4*4] = v;
            }
            __syncthreads();
            const float* Yj = YL[j];
            #pragma unroll 8
            for (int k = 0; k < 64; ++k){
                float4 av = *(const float4*)&At[k*65 + ty*4];
                float4 yv = *(const float4*)&Yj[k*65 + tx*4];
                float ar[4] = {av.x,av.y,av.z,av.w};
                float yr[4] = {yv.x,yv.y,yv.z,yv.w};
                #pragma unroll
                for (int a = 0; a < 4; ++a)
                    #pragma unroll
                    for (int b = 0; b < 4; ++b)
                        acc[a][b] = fmaf(-ar[a], yr[b], acc[a][b]);
            }
        }
        __syncthreads();
        #pragma unroll
        for (int a = 0; a < 4; ++a){
            float4 v; v.x=acc[a][0]; v.y=acc[a][1]; v.z=acc[a][2]; v.w=acc[a][3];
            *(float4*)&RL[(ty*4 + a)*65 + tx*4] = v;
        }
        for (int idx = tid; idx < 1024; idx += 256){
            int k = idx >> 4, r4 = idx & 15;
            float4 v = *(const float4*)&WTg[(size_t)bi*4096 + k*64 + r4*4];
            *(float4*)&At[k*65 + r4*4] = v;
        }
        __syncthreads();
        float out[4][4] = {};
        #pragma unroll 8
        for (int k = 0; k < 64; ++k){
            float4 av = *(const float4*)&At[k*65 + ty*4];
            float4 rv = *(const float4*)&RL[k*65 + tx*4];
            float ar[4] = {av.x,av.y,av.z,av.w};
            float rr[4] = {rv.x,rv.y,rv.z,rv.w};
            #pragma unroll
            for (int a = 0; a < 4; ++a)
                #pragma unroll
                for (int b = 0; b < 4; ++b)
                    out[a][b] = fmaf(ar[a], rr[b], out[a][b]);
        }
        float* Yi = YL[bi];
        #pragma unroll
        for (int a = 0; a < 4; ++a){
            float4 v; v.x=out[a][0]; v.y=out[a][1]; v.z=out[a][2]; v.w=out[a][3];
            *(float4*)&Yi[(ty*4 + a)*65 + tx*4] = v;
        }
    }
    for (int bi = 3; bi >= 0; --bi){
        __syncthreads();
        #pragma unroll
        for (int a = 0; a < 4; ++a){
            float4 v = *(const float4*)&YL[bi][(ty*4 + a)*65 + tx*4];
            acc[a][0]=v.x; acc[a][1]=v.y; acc[a][2]=v.z; acc[a][3]=v.w;
        }
        for (int j = bi+1; j < 4; ++j){
            __syncthreads();
            for (int idx = tid; idx < 1024; idx += 256){
                int k = idx >> 4, r4 = idx & 15;
                float4 v = *(const float4*)&Gn[(size_t)(j*64 + k)*256 + bi*64 + r4*4];
                *(float4*)&At[k*65 + r4*4] = v;
            }
            __syncthreads();
            const float* Zj = YL[j];
            #pragma unroll 8
            for (int k = 0; k < 64; ++k){
                float4 av = *(const float4*)&At[k*65 + ty*4];
                float4 zv = *(const float4*)&Zj[k*65 + tx*4];
                float ar[4] = {av.x,av.y,av.z,av.w};
                float zr[4] = {zv.x,zv.y,zv.z,zv.w};
                #pragma unroll
                for (int a = 0; a < 4; ++a)
                    #pragma unroll
                    for (int b = 0; b < 4; ++b)
                        acc[a][b] = fmaf(-ar[a], zr[b], acc[a][b]);
            }
        }
        __syncthreads();
        #pragma unroll
        for (int a = 0; a < 4; ++a){
            float4 v; v.x=acc[a][0]; v.y=acc[a][1]; v.z=acc[a][2]; v.w=acc[a][3];
            *(float4*)&RL[(ty*4 + a)*65 + tx*4] = v;
        }
        for (int idx = tid; idx < 1024; idx += 256){
            int k = idx >> 4, r4 = idx & 15;
            float4 v = *(const float4*)&Wg[(size_t)bi*4096 + k*64 + r4*4];
            *(float4*)&At[k*65 + r4*4] = v;
        }
        __syncthreads();
        float out[4][4] = {};
        #pragma unroll 8
        for (int k = 0; k < 64; ++k){
            float4 av = *(const float4*)&At[k*65 + ty*4];
            float4 rv = *(const float4*)&RL[k*65 + tx*4];
            float ar[4] = {av.x,av.y,av.z,av.w};
            float rr[4] = {rv.x,rv.y,rv.z,rv.w};
            #pragma unroll
            for (int a = 0; a < 4; ++a)
                #pragma unroll
                for (int b = 0; b < 4; ++b)
                    out[a][b] = fmaf(ar[a], rr[b], out[a][b]);
        }
        float* Zi = YL[bi];
        #pragma unroll
        for (int a = 0; a < 4; ++a){
            float4 v; v.x=out[a][0]; v.y=out[a][1]; v.z=out[a][2]; v.w=out[a][3];
            *(float4*)&Zi[(ty*4 + a)*65 + tx*4] = v;
            *(float4*)&Zb[(size_t)(bi*64 + ty*4 + a)*DIMD + tx*4] = v;
        }
    }
}

// ---- final GEMM: trans[d][e] = sum_c Bm[c][d] * Z[c][e] ----
__global__ __launch_bounds__(256) void k_gemmE(const float* __restrict__ ws, float* __restrict__ out){
    int bx = blockIdx.x; int et = bx & 7, dt = (bx >> 3) & 7, n = bx >> 6;
    int tid = threadIdx.x;
    __shared__ float Bl[256*64];
    __shared__ float Zl[256*64];
    const float* Bm = ws + O_BM + (size_t)n*256*DIMD;
    const float* Zb = ws + O_ZB + (size_t)n*256*DIMD;
    for (int idx = tid; idx < 16384; idx += 256){
        int c = idx >> 6, dd = idx & 63;
        Bl[idx] = Bm[(size_t)c*DIMD + dt*64 + dd];
        Zl[idx] = Zb[(size_t)c*DIMD + et*64 + dd];
    }
    __syncthreads();
    int td = tid & 15, te = tid >> 4;
    float acc[4][4] = {};
    for (int c = 0; c < 256; ++c){
        float4 bv = *(const float4*)&Bl[c*64 + td*4];
        float4 zv = *(const float4*)&Zl[c*64 + te*4];
        float b4[4] = {bv.x, bv.y, bv.z, bv.w};
        float z4[4] = {zv.x, zv.y, zv.z, zv.w};
        #pragma unroll
        for (int r = 0; r < 4; ++r)
            #pragma unroll
            for (int s = 0; s < 4; ++s) acc[r][s] = fmaf(b4[r], z4[s], acc[r][s]);
    }
    float* ob = out + (size_t)n*262144 + (size_t)(dt*64 + td*4)*DIMD + et*64 + te*4;
    #pragma unroll
    for (int r = 0; r < 4; ++r){
        float4 o; o.x = acc[r][0]; o.y = acc[r][1]; o.z = acc[r][2]; o.w = acc[r][3];
        *(float4*)&ob[(size_t)r*DIMD] = o;
    }
}

extern "C" void kernel_launch(void* const* d_in, const int* in_sizes, int n_in,
                              void* d_out, int out_size, void* d_ws, size_t ws_size,
                              hipStream_t stream){
    const float* src = (const float*)d_in[0];
    const float* tgt = (const float*)d_in[1];
    float* ws  = (float*)d_ws;
    float* out = (float*)d_out;

    k_init<<<256, 256, 0, stream>>>(src, tgt, ws);
    k_ptsT<<<8192, 256, 0, stream>>>(src, tgt, ws);

    for (int it = 0; it < KMIT; ++it){
        k_assign<<<1024, 256, 0, stream>>>(src, tgt,
                                           ws + O_CTG, ws + O_SQC, ws + O_SQP,
                                           (u64*)(ws + O_BEST));
        k_sums<<<256, 256, 0, stream>>>(ws);
        k_newc<<<64, 256, 0, stream>>>(ws);
    }

    hipMemsetAsync((char*)d_ws + O_CNT2*4, 0, 8*256*4, stream);
    k_ctn<<<512, 256, 0, stream>>>(ws);
    k_map<<<128, 256, 0, stream>>>(ws);
    k_bmat<<<64, 256, 0, stream>>>(ws);
    k_gram<<<64, 256, 0, stream>>>(ws);
    for (int kb = 0; kb < 4; ++kb){
        k_cholp<<<8, 256, 0, stream>>>(ws, kb);
        if (kb < 3) k_trail<<<dim3(8, 8), 256, 0, stream>>>(ws, kb);
    }
    k_dinv<<<8, 256, 0, stream>>>(ws);
    k_solve<<<dim3(8, 8), 256, 0, stream>>>(ws);
    k_gemmE<<<512, 256, 0, stream>>>(ws, out);
}

// Round 16
// 2317.660 us; speedup vs baseline: 1.1212x; 1.1212x over previous
//
#include <hip/hip_runtime.h>

typedef unsigned int u32;
typedef unsigned long long u64;

#define NPTS  1024
#define DIMD  512
#define KCL   64
#define KMIT  10

// ---- workspace layout (element offsets, all 4-byte elems) ----
constexpr size_t O_CTG  = 0;                        // [64 runs][512 d][64 c]
constexpr size_t O_SUMS = O_CTG  + 64ull*512*64;    // [64][64 c][512 d] (reused: PS0, then CS)
constexpr size_t O_CNT  = O_SUMS + 64ull*64*512;    // [64][64] int
constexpr size_t O_SQC  = O_CNT  + 64ull*64;        // [64][64]
constexpr size_t O_SQP  = O_SQC  + 64ull*64;        // [64][1024]
constexpr size_t O_ASG  = O_SQP  + 64ull*1024;      // [64][1024] int (dead; kept for layout)
constexpr size_t O_CTN  = O_ASG  + 64ull*1024;      // [8 n][256 c][512 d]
constexpr size_t O_Y    = O_CTN  + 8ull*256*512;    // [8][4][4][64] int
constexpr size_t O_CNT2 = O_Y    + 8ull*4*4*64;     // [8][256] int
constexpr size_t O_BM   = O_CNT2 + 8ull*256;        // [8][256 c][512 d]
constexpr size_t O_G    = O_BM   + 8ull*256*512;    // [8][256][256]
constexpr size_t O_LT   = O_G    + 8ull*256*256;    // [8][256][256]  LT[a][b]=L[b][a]
constexpr size_t O_YB   = O_LT   + 8ull*256*256;    // [8][256][512] (reused: W/WT)
constexpr size_t O_ZB   = O_YB   + 8ull*256*512;    // [8][256][512]
constexpr size_t O_PTST = O_ZB   + 8ull*256*512;    // [64][1024 p][512 d]

// partial sums for kmeans (loop-phase only).
constexpr size_t O_PS0 = O_SUMS;                    // [64][64 c][512 d]
constexpr size_t O_PS1 = O_CTN;                     // [64][64 c][512 d]
static_assert(O_PS1 + 64ull*64*512 <= O_G, "PS1 overlay must fit before O_G");

// per-block argmin candidates (loop-phase only): overlay O_G (post-loop buffer).
constexpr size_t O_BEST = O_G;

// post-loop overlays:
constexpr size_t O_CS = O_SUMS;                     // [8 n][4 i][64 k][512 d] source centers rows
constexpr size_t O_W  = O_YB;                       // [8][4][64 r][64 k]  W = inv(L_ii)
constexpr size_t O_WT = O_YB + 8ull*4*64*64;        // [8][4][64 k][64 r]  W^T

__device__ __forceinline__ const float* run_base(const float* s, const float* t, int run){
    const float* b = (run < 32) ? s : t;
    return b + (size_t)(run & 31) * (DIMD * NPTS);
}
// monotonic pack of (d2, idx): min picks smallest d2, ties -> smallest idx (matches jnp.argmin)
__device__ __forceinline__ u64 dpack(float d2, int c){
    u32 u = __float_as_uint(d2);
    u = (u & 0x80000000u) ? ~u : (u | 0x80000000u);
    return ((u64)u << 32) | (u32)c;
}
__device__ __forceinline__ float rdlane(float v, int l){
    return __uint_as_float(__builtin_amdgcn_readlane(__float_as_uint(v), l));
}

// ---- init: sqp (per-point |p|^2), initial centers (first 64 pts), sqc, zero cnt ----
__global__ __launch_bounds__(256) void k_init(const float* __restrict__ src, const float* __restrict__ tgt,
                                              float* __restrict__ ws){
    int bx = blockIdx.x; int run = bx >> 2, q = bx & 3;
    int tid = threadIdx.x;
    const float* base = run_base(src, tgt, run);
    int p = q*256 + tid;
    float acc = 0.f;
    for (int d = 0; d < DIMD; ++d){
        float v = base[(size_t)d*NPTS + p];
        acc = fmaf(v, v, acc);
    }
    ws[O_SQP + run*NPTS + p] = acc;
    if (q == 0){
        if (tid < KCL) ws[O_SQC + run*KCL + tid] = acc;
        if (tid < KCL) ((int*)(ws + O_CNT))[run*KCL + tid] = 0;
        for (int idx = tid; idx < DIMD*KCL; idx += 256){
            int d = idx >> 6, c = idx & 63;
            ws[O_CTG + (size_t)run*DIMD*KCL + idx] = base[(size_t)d*NPTS + c];
        }
    }
}

// ---- build transposed points copy [run][p][d] for deterministic sums ----
__global__ __launch_bounds__(256) void k_ptsT(const float* __restrict__ src, const float* __restrict__ tgt,
                                              float* __restrict__ ws){
    int bx = blockIdx.x; int dt = bx & 7, pt = (bx >> 3) & 15, run = bx >> 7;
    int tid = threadIdx.x, lane = tid & 63, r4 = tid >> 6;
    const float* base = run_base(src, tgt, run);
    __shared__ float t[64*65];
    for (int pass = 0; pass < 16; ++pass){
        int r = pass*4 + r4;
        t[r*65 + lane] = base[(size_t)(dt*64 + r)*NPTS + pt*64 + lane];
    }
    __syncthreads();
    for (int pass = 0; pass < 16; ++pass){
        int p = pass*4 + r4;
        ws[O_PTST + ((size_t)run*NPTS + pt*64 + p)*DIMD + dt*64 + lane] = t[lane*65 + p];
    }
}

// ---- kmeans assignment, center-split: 1024 blocks (4/CU, 4 waves/SIMD), 8-dim ping-pong ----
__global__ __launch_bounds__(256, 4) void k_assign(const float* __restrict__ src, const float* __restrict__ tgt,
                                                   const float* __restrict__ ctr, const float* __restrict__ sqc,
                                                   const float* __restrict__ sqp,
                                                   u64* __restrict__ bestg){
    int bxx = blockIdx.x;                    // 0..1023
    int cb  = (bxx >> 3) & 1;
    int w   = ((bxx >> 4) << 3) | (bxx & 7); // 0..511
    int run = w >> 3, qt = w & 7;
    int tid = threadIdx.x, lane = tid & 63;
    int g = __builtin_amdgcn_readfirstlane(tid >> 6);
    int c0 = cb*32 + g*8;                    // this wave's 8 centers
    const float* base = run_base(src, tgt, run);
    const float* cg = ctr + (size_t)run*DIMD*KCL + c0;
    int p0 = qt*128 + 2*lane;                // points p0, p0+1
    float acc[2][8] = {};
    __shared__ u64 red[4][128];

#define LOADP(P, DB) { \
    _Pragma("unroll") \
    for (int u = 0; u < 8; ++u) \
        P[u] = *(const float2*)&base[(size_t)((DB)*8 + u)*NPTS + p0]; }

#define COMPUTE(P, DB) { \
    _Pragma("unroll") \
    for (int u = 0; u < 8; ++u){ \
        const float4* cp = (const float4*)(cg + (size_t)((DB)*8 + u)*KCL); \
        float4 c0v = cp[0], c1v = cp[1]; \
        float cv[8] = {c0v.x,c0v.y,c0v.z,c0v.w, c1v.x,c1v.y,c1v.z,c1v.w}; \
        _Pragma("unroll") \
        for (int cl = 0; cl < 8; ++cl){ \
            acc[0][cl] = fmaf(P[u].x, cv[cl], acc[0][cl]); \
            acc[1][cl] = fmaf(P[u].y, cv[cl], acc[1][cl]); \
        } \
    } }

    float2 pa[8], pb[8];
    LOADP(pa, 0);
    for (int db = 0; db < 64; db += 2){
        if (db + 1 < 64) LOADP(pb, db + 1);
        COMPUTE(pa, db);
        if (db + 2 < 64) LOADP(pa, db + 2);
        COMPUTE(pb, db + 1);
    }
#undef LOADP
#undef COMPUTE

    const float* sqcg = sqc + run*KCL + c0;
    float sq[8];
    #pragma unroll
    for (int q = 0; q < 8; ++q) sq[q] = sqcg[q];
    float2 sq2 = *(const float2*)&sqp[run*NPTS + p0];
    #pragma unroll
    for (int s = 0; s < 2; ++s){
        float sqpv = s ? sq2.y : sq2.x;
        u64 best = dpack(sqpv + sq[0] - 2.f*acc[s][0], c0);
        #pragma unroll
        for (int cl = 1; cl < 8; ++cl){
            u64 k2 = dpack(sqpv + sq[cl] - 2.f*acc[s][cl], c0 + cl);
            best = (k2 < best) ? k2 : best;
        }
        red[g][2*lane + s] = best;
    }
    __syncthreads();
    if (tid < 128){
        u64 b = red[0][tid];
        #pragma unroll
        for (int g2 = 1; g2 < 4; ++g2){ u64 k2 = red[g2][tid]; b = (k2 < b) ? k2 : b; }
        bestg[(((size_t)(run*8 + qt)*128 + tid) << 1) + cb] = b;
    }
}

// ---- kmeans partial sums + inline argmin-combine ----
__global__ __launch_bounds__(256) void k_sums(float* __restrict__ ws){
    int bx = blockIdx.x; int pg = bx & 1, dh = (bx >> 1) & 1, run = bx >> 2;
    int tid = threadIdx.x;
    __shared__ float sm[KCL*256];
    __shared__ int a[512];
    const u64* bestg = (const u64*)(ws + O_BEST);
    int* cnt = (int*)(ws + O_CNT);
    for (int idx = tid; idx < 512; idx += 256){
        int p = pg*512 + idx;
        int qt = p >> 7, t = p & 127;
        const u64* bp = bestg + (((size_t)(run*8 + qt)*128 + t) << 1);
        u64 x = bp[0], y = bp[1];
        u64 m = (y < x) ? y : x;
        int c = (int)(m & 0xffffffffu);
        a[idx] = c;
        if (dh == 0) atomicAdd(&cnt[run*KCL + c], 1);
    }
    for (int idx = tid; idx < KCL*256; idx += 256) sm[idx] = 0.f;
    __syncthreads();
    const float* pT = ws + O_PTST + ((size_t)run*NPTS + pg*512)*DIMD + dh*256 + tid;
    for (int p = 0; p < 512; p += 4){
        float v0 = pT[(size_t)(p+0)*DIMD], v1 = pT[(size_t)(p+1)*DIMD];
        float v2 = pT[(size_t)(p+2)*DIMD], v3 = pT[(size_t)(p+3)*DIMD];
        sm[a[p+0]*256 + tid] += v0;
        sm[a[p+1]*256 + tid] += v1;
        sm[a[p+2]*256 + tid] += v2;
        sm[a[p+3]*256 + tid] += v3;
    }
    __syncthreads();
    size_t psx = pg ? O_PS1 : O_PS0;
    for (int c = 0; c < KCL; ++c)
        ws[psx + ((size_t)run*KCL + c)*DIMD + dh*256 + tid] = sm[c*256 + tid];
}

// ---- kmeans center update + sqc + zero cnt (deterministic: ps0+ps1) ----
__global__ __launch_bounds__(256) void k_newc(float* __restrict__ ws){
    int run = blockIdx.x, tid = threadIdx.x;
    __shared__ float sm2[KCL*65];
    __shared__ int cl[KCL];
    int* cnt = (int*)(ws + O_CNT);
    if (tid < KCL) cl[tid] = cnt[run*KCL + tid];
    __syncthreads();
    if (tid < KCL) cnt[run*KCL + tid] = 0;
    float sqa = 0.f;
    for (int dc = 0; dc < 8; ++dc){
        for (int idx = tid; idx < KCL*64; idx += 256){
            int c = idx >> 6, dl = idx & 63;
            size_t o = ((size_t)run*KCL + c)*DIMD + dc*64 + dl;
            sm2[c*65 + dl] = ws[O_PS0 + o] + ws[O_PS1 + o];
        }
        __syncthreads();
        for (int idx = tid; idx < KCL*64; idx += 256){
            int dl = idx >> 6, c = idx & 63, d = dc*64 + dl;
            size_t gi = O_CTG + (size_t)run*DIMD*KCL + d*KCL + c;
            float old = ws[gi];
            int cc = cl[c];
            float nv = (cc > 0) ? sm2[c*65 + dl] / (float)cc : old;
            ws[gi] = nv;
            sm2[c*65 + dl] = nv;
        }
        __syncthreads();
        if (tid < KCL){
            for (int dl = 0; dl < 64; ++dl){ float v = sm2[tid*65 + dl]; sqa = fmaf(v, v, sqa); }
        }
        __syncthreads();
    }
    if (tid < KCL) ws[O_SQC + run*KCL + tid] = sqa;
}

// ---- regroup centers to row-major: target -> CTN [n][256c][512d]; source -> CS [n][4i][64k][512d] ----
__global__ __launch_bounds__(256) void k_ctn(float* __restrict__ ws){
    int bx = blockIdx.x; int dc = bx & 7, jj = (bx >> 3) & 3, n = (bx >> 5) & 7, st = bx >> 8;
    int run = st ? (jj*8 + n) : (32 + jj*8 + n);
    int tid = threadIdx.x, lane = tid & 63, r4 = tid >> 6;
    __shared__ float t[64*65];
    for (int pass = 0; pass < 16; ++pass){
        int r = pass*4 + r4;
        t[r*65 + lane] = ws[O_CTG + (size_t)run*DIMD*KCL + (dc*64 + r)*KCL + lane];
    }
    __syncthreads();
    size_t dstbase = st ? (O_CS  + ((size_t)(n*4 + jj)*64)*DIMD)
                        : (O_CTN + ((size_t)n*256 + jj*64)*DIMD);
    for (int pass = 0; pass < 16; ++pass){
        int l = pass*4 + r4;
        ws[dstbase + (size_t)l*DIMD + dc*64 + lane] = t[lane*65 + l];
    }
}

// ---- source->target center matching ----
__global__ __launch_bounds__(256) void k_map(float* __restrict__ ws){
    int bx = blockIdx.x; int j = bx & 3, i = (bx >> 2) & 3, n = bx >> 4;
    int run_s = i*8 + n, run_t = 32 + j*8 + n;
    int tid = threadIdx.x, lane = tid & 63;
    int g = __builtin_amdgcn_readfirstlane(tid >> 6);
    const float* cgs = ws + O_CTG + (size_t)run_s*DIMD*KCL + lane;
    const float* cgt = ws + O_CTG + (size_t)run_t*DIMD*KCL + g*16;
    float acc[16] = {};
    for (int d = 0; d < DIMD; ++d){
        float csv = cgs[d*KCL];
        const float4* cp = (const float4*)(cgt + d*KCL);
        float4 c0=cp[0], c1=cp[1], c2=cp[2], c3=cp[3];
        float cv[16] = {c0.x,c0.y,c0.z,c0.w, c1.x,c1.y,c1.z,c1.w,
                        c2.x,c2.y,c2.z,c2.w, c3.x,c3.y,c3.z,c3.w};
        #pragma unroll
        for (int cl = 0; cl < 16; ++cl) acc[cl] = fmaf(csv, cv[cl], acc[cl]);
    }
    float sqs = ws[O_SQC + run_s*KCL + lane];
    const float* sqtp = ws + O_SQC + run_t*KCL + g*16;
    u64 best = dpack(sqs + sqtp[0] - 2.f*acc[0], g*16);
    #pragma unroll
    for (int cl = 1; cl < 16; ++cl){
        u64 k2 = dpack(sqs + sqtp[cl] - 2.f*acc[cl], g*16 + cl);
        best = (k2 < best) ? k2 : best;
    }
    __shared__ u64 red[4][64];
    red[g][lane] = best;
    __syncthreads();
    if (tid < 64){
        u64 b = red[0][tid];
        #pragma unroll
        for (int g2 = 1; g2 < 4; ++g2){ u64 k2 = red[g2][tid]; b = (k2 < b) ? k2 : b; }
        int l = (int)(b & 0xffffffffu);
        int* yv   = (int*)(ws + O_Y);
        int* cnt2 = (int*)(ws + O_CNT2);
        yv[((n*4 + i)*4 + j)*64 + tid] = l;
        atomicAdd(&cnt2[n*256 + j*64 + l], 1);
    }
}

// ---- B matrix: serial gather-accumulate over 256 sources, coalesced rows, no atomics ----
__global__ __launch_bounds__(256) void k_bmat(float* __restrict__ ws){
    int bx = blockIdx.x; int dh = bx & 1, j = (bx >> 1) & 3, n = bx >> 3;
    int tid = threadIdx.x;
    __shared__ float Bacc[KCL*256];   // 64 KB
    __shared__ int yl[256];
    __shared__ int c2[KCL];
    const int* yv   = (const int*)(ws + O_Y);
    const int* cnt2 = (const int*)(ws + O_CNT2);
    { int i = tid >> 6, k = tid & 63; yl[tid] = yv[((n*4 + i)*4 + j)*64 + k]; }
    if (tid < KCL) c2[tid] = cnt2[n*256 + j*64 + tid];
    for (int idx = tid; idx < KCL*256; idx += 256) Bacc[idx] = 0.f;
    __syncthreads();
    const float* cs = ws + O_CS + (size_t)(n*4)*64*DIMD + dh*256 + tid;
    #pragma unroll 4
    for (int s = 0; s < 256; ++s){
        int l = yl[s];
        float v = cs[(size_t)s*DIMD];
        Bacc[l*256 + tid] += v;
    }
    __syncthreads();
    for (int l = 0; l < KCL; ++l){
        int cc = c2[l]; if (cc < 1) cc = 1;
        ws[O_BM + ((size_t)n*256 + j*64 + l)*DIMD + dh*256 + tid] = Bacc[l*256 + tid] / (float)cc;
    }
}

// ---- masked Gram: tiled A·A^T over CTN rows (coalesced, L2-friendly) ----
// grid (16 = 4x4 tiles, 8 n), 256 threads, 4x4 register tiles, LDS-staged panels.
__global__ __launch_bounds__(256) void k_gram(float* __restrict__ ws){
    int bx = blockIdx.x; int ti = bx & 3, tj = (bx >> 2) & 3, n = bx >> 4;
    int tid = threadIdx.x;
    int tx = tid & 15, ty = tid >> 4;
    const float* A = ws + O_CTN + (size_t)n*256*DIMD;
    __shared__ __align__(16) float Ai[64*65];
    __shared__ __align__(16) float Aj[64*65];
    float acc[4][4] = {};
    for (int kc = 0; kc < 8; ++kc){
        __syncthreads();
        for (int idx = tid; idx < 1024; idx += 256){
            int r = idx >> 4, c4 = idx & 15;
            *(float4*)&Ai[r*65 + c4*4] = *(const float4*)&A[(size_t)(ti*64 + r)*DIMD + kc*64 + c4*4];
            *(float4*)&Aj[r*65 + c4*4] = *(const float4*)&A[(size_t)(tj*64 + r)*DIMD + kc*64 + c4*4];
        }
        __syncthreads();
        #pragma unroll 8
        for (int k = 0; k < 64; ++k){
            float ar[4], br[4];
            #pragma unroll
            for (int a = 0; a < 4; ++a) ar[a] = Ai[(ty*4 + a)*65 + k];
            #pragma unroll
            for (int b = 0; b < 4; ++b) br[b] = Aj[(tx*4 + b)*65 + k];
            #pragma unroll
            for (int a = 0; a < 4; ++a)
                #pragma unroll
                for (int b = 0; b < 4; ++b)
                    acc[a][b] = fmaf(ar[a], br[b], acc[a][b]);
        }
    }
    const int* cnt2 = (const int*)(ws + O_CNT2);
    float* Gp = ws + O_G + (size_t)n*65536;
    #pragma unroll
    for (int a = 0; a < 4; ++a){
        int row = ti*64 + ty*4 + a;
        bool ur = cnt2[n*256 + row] > 0;
        #pragma unroll
        for (int b = 0; b < 4; ++b){
            int col = tj*64 + tx*4 + b;
            bool uc = cnt2[n*256 + col] > 0;
            float v = (ur && uc) ? acc[a][b] : ((row == col) ? 1.f : 0.f);
            Gp[(size_t)row*256 + col] = v;
        }
    }
}

// ---- Cholesky panel: register-lockstep fused diag factor + panel solve (one kb) ----
__global__ __launch_bounds__(256, 1) void k_cholp(float* __restrict__ ws, int kb){
    int n = blockIdx.x, tid = threadIdx.x;
    int lane = tid & 63, wv = tid >> 6;
    float* Gn  = ws + O_G  + (size_t)n*65536;
    float* LTn = ws + O_LT + (size_t)n*65536;
    int c0 = kb*64, r1 = c0 + 64, rem = 256 - r1;

    float dreg[64];
    {
        const float* grow = Gn + (size_t)(c0+lane)*256 + c0;
        #pragma unroll
        for (int j4 = 0; j4 < 16; ++j4){
            float4 v = *(const float4*)&grow[j4*4];
            dreg[j4*4+0]=v.x; dreg[j4*4+1]=v.y; dreg[j4*4+2]=v.z; dreg[j4*4+3]=v.w;
        }
    }
    float preg[64];
    int prow = (wv-1)*64 + lane;
    bool pact = (wv >= 1) && (prow < rem);
    {
        const float* growp = Gn + (size_t)(r1+prow)*256 + c0;
        #pragma unroll
        for (int j4 = 0; j4 < 16; ++j4){
            if (pact){
                float4 v = *(const float4*)&growp[j4*4];
                preg[j4*4+0]=v.x; preg[j4*4+1]=v.y; preg[j4*4+2]=v.z; preg[j4*4+3]=v.w;
            } else {
                preg[j4*4+0]=0.f; preg[j4*4+1]=0.f; preg[j4*4+2]=0.f; preg[j4*4+3]=0.f;
            }
        }
    }
    #pragma unroll
    for (int k = 0; k < 64; ++k){
        float dkk = sqrtf(fmaxf(rdlane(dreg[k], k), 1e-30f));
        float inv = 1.f / dkk;
        dreg[k] = (lane == k) ? dkk : dreg[k]*inv;
        preg[k] *= inv;
        #pragma unroll
        for (int j = k+1; j < 64; ++j){
            float s = rdlane(dreg[k], j);
            dreg[j] = fmaf(-dreg[k], s, dreg[j]);
            preg[j] = fmaf(-preg[k], s, preg[j]);
        }
    }
    if (wv == 0){
        float* grow = Gn + (size_t)(c0+lane)*256 + c0;
        #pragma unroll
        for (int j4 = 0; j4 < 16; ++j4){
            float4 v; v.x=dreg[j4*4+0]; v.y=dreg[j4*4+1]; v.z=dreg[j4*4+2]; v.w=dreg[j4*4+3];
            *(float4*)&grow[j4*4] = v;
        }
    }
    if (pact){
        float* growp = Gn + (size_t)(r1+prow)*256 + c0;
        #pragma unroll
        for (int j4 = 0; j4 < 16; ++j4){
            float4 v; v.x=preg[j4*4+0]; v.y=preg[j4*4+1]; v.z=preg[j4*4+2]; v.w=preg[j4*4+3];
            *(float4*)&growp[j4*4] = v;
        }
        float* ltp = LTn + (size_t)c0*256 + r1 + prow;
        #pragma unroll
        for (int j = 0; j < 64; ++j) ltp[(size_t)j*256] = preg[j];
    }
}

// ---- trailing update for panel kb, wide-parallel: C -= Lp * Lp^T (lower 4x4 tiles) ----
__global__ __launch_bounds__(256) void k_trail(float* __restrict__ ws, int kb){
    int n = blockIdx.y;
    int c0 = kb*64, r1 = c0 + 64, rem = 256 - r1;
    int nt4 = rem >> 2;
    int ntiles = nt4*(nt4+1)/2;
    float* Gn = ws + O_G + (size_t)n*65536;
    for (int t = blockIdx.x*256 + threadIdx.x; t < ntiles; t += gridDim.x*256){
        int ti = (int)((sqrtf(8.f*(float)t + 1.f) - 1.f) * 0.5f);
        while ((ti+1)*(ti+2)/2 <= t) ++ti;
        while (ti*(ti+1)/2 > t) --ti;
        int tj = t - ti*(ti+1)/2;
        int i0 = ti*4, j0 = tj*4;
        const float* Li = Gn + (size_t)(r1+i0)*256 + c0;
        const float* Lj = Gn + (size_t)(r1+j0)*256 + c0;
        float acc[4][4] = {};
        for (int k = 0; k < 64; k += 4){
            float4 ar4[4], br4[4];
            #pragma unroll
            for (int r = 0; r < 4; ++r) ar4[r] = *(const float4*)&Li[(size_t)r*256 + k];
            #pragma unroll
            for (int s = 0; s < 4; ++s) br4[s] = *(const float4*)&Lj[(size_t)s*256 + k];
            #pragma unroll
            for (int q = 0; q < 4; ++q){
                float aq[4] = { q==0?ar4[0].x:q==1?ar4[0].y:q==2?ar4[0].z:ar4[0].w,
                                q==0?ar4[1].x:q==1?ar4[1].y:q==2?ar4[1].z:ar4[1].w,
                                q==0?ar4[2].x:q==1?ar4[2].y:q==2?ar4[2].z:ar4[2].w,
                                q==0?ar4[3].x:q==1?ar4[3].y:q==2?ar4[3].z:ar4[3].w };
                float bq[4] = { q==0?br4[0].x:q==1?br4[0].y:q==2?br4[0].z:br4[0].w,
                                q==0?br4[1].x:q==1?br4[1].y:q==2?br4[1].z:br4[1].w,
                                q==0?br4[2].x:q==1?br4[2].y:q==2?br4[2].z:br4[2].w,
                                q==0?br4[3].x:q==1?br4[3].y:q==2?br4[3].z:br4[3].w };
                #pragma unroll
                for (int r = 0; r < 4; ++r)
                    #pragma unroll
                    for (int s = 0; s < 4; ++s)
                        acc[r][s] = fmaf(aq[r], bq[s], acc[r][s]);
            }
        }
        #pragma unroll
        for (int r = 0; r < 4; ++r){
            float* grow = Gn + (size_t)(r1+i0+r)*256 + r1 + j0;
            #pragma unroll
            for (int s = 0; s < 4; ++s) grow[s] -= acc[r][s];
        }
    }
}

// ---- diag-block inverses: W_i = inv(L_ii), column-parallel per lane ----
__global__ __launch_bounds__(256, 1) void k_dinv(float* __restrict__ ws){
    int n = blockIdx.x, tid = threadIdx.x;
    int lane = tid & 63, kb = tid >> 6;
    const float* Gn = ws + O_G + (size_t)n*65536;
    __shared__ __align__(16) float DlT[4][64*65];   // DlT[kb][k*65+i] = L[i][k]
    for (int idx = lane; idx < 1024; idx += 64){
        int r = idx >> 4, c4 = idx & 15;
        float4 v = *(const float4*)&Gn[(size_t)(kb*64 + r)*256 + kb*64 + c4*4];
        DlT[kb][(c4*4+0)*65 + r] = v.x;
        DlT[kb][(c4*4+1)*65 + r] = v.y;
        DlT[kb][(c4*4+2)*65 + r] = v.z;
        DlT[kb][(c4*4+3)*65 + r] = v.w;
    }
    __syncthreads();
    float x[64];
    #pragma unroll
    for (int i = 0; i < 64; ++i) x[i] = (i == lane) ? 1.f : 0.f;
    const float* Dk = DlT[kb];
    #pragma unroll
    for (int k = 0; k < 64; ++k){
        float invd = 1.f / Dk[k*65 + k];
        x[k] *= invd;
        #pragma unroll
        for (int i = k+1; i < 64; ++i)
            x[i] = fmaf(-Dk[k*65 + i], x[k], x[i]);
    }
    float* Wg  = ws + O_W  + ((size_t)n*4 + kb)*4096;
    float* WTg = ws + O_WT + ((size_t)n*4 + kb)*4096;
    #pragma unroll
    for (int r = 0; r < 64; ++r) Wg[r*64 + lane] = x[r];
    #pragma unroll
    for (int r4 = 0; r4 < 16; ++r4){
        float4 v; v.x=x[r4*4+0]; v.y=x[r4*4+1]; v.z=x[r4*4+2]; v.w=x[r4*4+3];
        *(float4*)&WTg[lane*64 + r4*4] = v;
    }
}

// ---- triangular solves as block GEMMs: G Z = Ct via L Y = Ct; L^T Z = Y ----
__global__ __launch_bounds__(256, 1) void k_solve(float* __restrict__ ws){
    int n = blockIdx.x, cg = blockIdx.y;
    int tid = threadIdx.x;
    int tx = tid & 15, ty = tid >> 4;
    const float* Gn  = ws + O_G  + (size_t)n*65536;
    const float* LTn = ws + O_LT + (size_t)n*65536;
    const float* Ct  = ws + O_CTN + (size_t)n*256*DIMD + (size_t)cg*64;
    const float* Wg  = ws + O_W  + (size_t)n*4*4096;
    const float* WTg = ws + O_WT + (size_t)n*4*4096;
    float* Zb = ws + O_ZB + (size_t)n*256*DIMD + (size_t)cg*64;

    __shared__ __align__(16) float YL[4][64*65];
    __shared__ __align__(16) float At[64*65];
    __shared__ __align__(16) float RL[64*65];

    float acc[4][4];
    for (int bi = 0; bi < 4; ++bi){
        #pragma unroll
        for (int a = 0; a < 4; ++a){
            float4 v = *(const float4*)&Ct[(size_t)(bi*64 + ty*4 + a)*DIMD + tx*4];
            acc[a][0]=v.x; acc[a][1]=v.y; acc[a][2]=v.z; acc[a][3]=v.w;
        }
        for (int j = 0; j < bi; ++j){
            __syncthreads();
            for (int idx = tid; idx < 1024; idx += 256){
                int k = idx >> 4, r4 = idx & 15;
                float4 v = *(const float4*)&LTn[(size_t)(j*64 + k)*256 + bi*64 + r4*4];
                *(float4*)&At[k*65 + r4*4] = v;
            }
            __syncthreads();
            const float* Yj = YL[j];
            #pragma unroll 8
            for (int k = 0; k < 64; ++k){
                float4 av = *(const float4*)&At[k*65 + ty*4];
                float4 yv = *(const float4*)&Yj[k*65 + tx*4];
                float ar[4] = {av.x,av.y,av.z,av.w};
                float yr[4] = {yv.x,yv.y,yv.z,yv.w};
                #pragma unroll
                for (int a = 0; a < 4; ++a)
                    #pragma unroll
                    for (int b = 0; b < 4; ++b)
                        acc[a][b] = fmaf(-ar[a], yr[b], acc[a][b]);
            }
        }
        __syncthreads();
        #pragma unroll
        for (int a = 0; a < 4; ++a){
            float4 v; v.x=acc[a][0]; v.y=acc[a][1]; v.z=acc[a][2]; v.w=acc[a][3];
            *(float4*)&RL[(ty*4 + a)*65 + tx*4] = v;
        }
        for (int idx = tid; idx < 1024; idx += 256){
            int k = idx >> 4, r4 = idx & 15;
            float4 v = *(const float4*)&WTg[(size_t)bi*4096 + k*64 + r4*4];
            *(float4*)&At[k*65 + r4*4] = v;
        }
        __syncthreads();
        float out[4][4] = {};
        #pragma unroll 8
        for (int k = 0; k < 64; ++k){
            float4 av = *(const float4*)&At[k*65 + ty*4];
            float4 rv = *(const float4*)&RL[k*65 + tx*4];
            float ar[4] = {av.x,av.y,av.z,av.w};
            float rr[4] = {rv.x,rv.y,rv.z,rv.w};
            #pragma unroll
            for (int a = 0; a < 4; ++a)
                #pragma unroll
                for (int b = 0; b < 4; ++b)
                    out[a][b] = fmaf(ar[a], rr[b], out[a][b]);
        }
        float* Yi = YL[bi];
        #pragma unroll
        for (int a = 0; a < 4; ++a){
            float4 v; v.x=out[a][0]; v.y=out[a][1]; v.z=out[a][2]; v.w=out[a][3];
            *(float4*)&Yi[(ty*4 + a)*65 + tx*4] = v;
        }
    }
    for (int bi = 3; bi >= 0; --bi){
        __syncthreads();
        #pragma unroll
        for (int a = 0; a < 4; ++a){
            float4 v = *(const float4*)&YL[bi][(ty*4 + a)*65 + tx*4];
            acc[a][0]=v.x; acc[a][1]=v.y; acc[a][2]=v.z; acc[a][3]=v.w;
        }
        for (int j = bi+1; j < 4; ++j){
            __syncthreads();
            for (int idx = tid; idx < 1024; idx += 256){
                int k = idx >> 4, r4 = idx & 15;
                float4 v = *(const float4*)&Gn[(size_t)(j*64 + k)*256 + bi*64 + r4*4];
                *(float4*)&At[k*65 + r4*4] = v;
            }
            __syncthreads();
            const float* Zj = YL[j];
            #pragma unroll 8
            for (int k = 0; k < 64; ++k){
                float4 av = *(const float4*)&At[k*65 + ty*4];
                float4 zv = *(const float4*)&Zj[k*65 + tx*4];
                float ar[4] = {av.x,av.y,av.z,av.w};
                float zr[4] = {zv.x,zv.y,zv.z,zv.w};
                #pragma unroll
                for (int a = 0; a < 4; ++a)
                    #pragma unroll
                    for (int b = 0; b < 4; ++b)
                        acc[a][b] = fmaf(-ar[a], zr[b], acc[a][b]);
            }
        }
        __syncthreads();
        #pragma unroll
        for (int a = 0; a < 4; ++a){
            float4 v; v.x=acc[a][0]; v.y=acc[a][1]; v.z=acc[a][2]; v.w=acc[a][3];
            *(float4*)&RL[(ty*4 + a)*65 + tx*4] = v;
        }
        for (int idx = tid; idx < 1024; idx += 256){
            int k = idx >> 4, r4 = idx & 15;
            float4 v = *(const float4*)&Wg[(size_t)bi*4096 + k*64 + r4*4];
            *(float4*)&At[k*65 + r4*4] = v;
        }
        __syncthreads();
        float out[4][4] = {};
        #pragma unroll 8
        for (int k = 0; k < 64; ++k){
            float4 av = *(const float4*)&At[k*65 + ty*4];
            float4 rv = *(const float4*)&RL[k*65 + tx*4];
            float ar[4] = {av.x,av.y,av.z,av.w};
            float rr[4] = {rv.x,rv.y,rv.z,rv.w};
            #pragma unroll
            for (int a = 0; a < 4; ++a)
                #pragma unroll
                for (int b = 0; b < 4; ++b)
                    out[a][b] = fmaf(ar[a], rr[b], out[a][b]);
        }
        float* Zi = YL[bi];
        #pragma unroll
        for (int a = 0; a < 4; ++a){
            float4 v; v.x=out[a][0]; v.y=out[a][1]; v.z=out[a][2]; v.w=out[a][3];
            *(float4*)&Zi[(ty*4 + a)*65 + tx*4] = v;
            *(float4*)&Zb[(size_t)(bi*64 + ty*4 + a)*DIMD + tx*4] = v;
        }
    }
}

// ---- final GEMM: trans[d][e] = sum_c Bm[c][d] * Z[c][e] ----
__global__ __launch_bounds__(256) void k_gemmE(const float* __restrict__ ws, float* __restrict__ out){
    int bx = blockIdx.x; int et = bx & 7, dt = (bx >> 3) & 7, n = bx >> 6;
    int tid = threadIdx.x;
    __shared__ float Bl[256*64];
    __shared__ float Zl[256*64];
    const float* Bm = ws + O_BM + (size_t)n*256*DIMD;
    const float* Zb = ws + O_ZB + (size_t)n*256*DIMD;
    for (int idx = tid; idx < 16384; idx += 256){
        int c = idx >> 6, dd = idx & 63;
        Bl[idx] = Bm[(size_t)c*DIMD + dt*64 + dd];
        Zl[idx] = Zb[(size_t)c*DIMD + et*64 + dd];
    }
    __syncthreads();
    int td = tid & 15, te = tid >> 4;
    float acc[4][4] = {};
    for (int c = 0; c < 256; ++c){
        float4 bv = *(const float4*)&Bl[c*64 + td*4];
        float4 zv = *(const float4*)&Zl[c*64 + te*4];
        float b4[4] = {bv.x, bv.y, bv.z, bv.w};
        float z4[4] = {zv.x, zv.y, zv.z, zv.w};
        #pragma unroll
        for (int r = 0; r < 4; ++r)
            #pragma unroll
            for (int s = 0; s < 4; ++s) acc[r][s] = fmaf(b4[r], z4[s], acc[r][s]);
    }
    float* ob = out + (size_t)n*262144 + (size_t)(dt*64 + td*4)*DIMD + et*64 + te*4;
    #pragma unroll
    for (int r = 0; r < 4; ++r){
        float4 o; o.x = acc[r][0]; o.y = acc[r][1]; o.z = acc[r][2]; o.w = acc[r][3];
        *(float4*)&ob[(size_t)r*DIMD] = o;
    }
}

extern "C" void kernel_launch(void* const* d_in, const int* in_sizes, int n_in,
                              void* d_out, int out_size, void* d_ws, size_t ws_size,
                              hipStream_t stream){
    const float* src = (const float*)d_in[0];
    const float* tgt = (const float*)d_in[1];
    float* ws  = (float*)d_ws;
    float* out = (float*)d_out;

    k_init<<<256, 256, 0, stream>>>(src, tgt, ws);
    k_ptsT<<<8192, 256, 0, stream>>>(src, tgt, ws);

    for (int it = 0; it < KMIT; ++it){
        k_assign<<<1024, 256, 0, stream>>>(src, tgt,
                                           ws + O_CTG, ws + O_SQC, ws + O_SQP,
                                           (u64*)(ws + O_BEST));
        k_sums<<<256, 256, 0, stream>>>(ws);
        k_newc<<<64, 256, 0, stream>>>(ws);
    }

    hipMemsetAsync((char*)d_ws + O_CNT2*4, 0, 8*256*4, stream);
    k_ctn<<<512, 256, 0, stream>>>(ws);
    k_map<<<128, 256, 0, stream>>>(ws);
    k_bmat<<<64, 256, 0, stream>>>(ws);
    k_gram<<<128, 256, 0, stream>>>(ws);
    for (int kb = 0; kb < 4; ++kb){
        k_cholp<<<8, 256, 0, stream>>>(ws, kb);
        if (kb < 3) k_trail<<<dim3(8, 8), 256, 0, stream>>>(ws, kb);
    }
    k_dinv<<<8, 256, 0, stream>>>(ws);
    k_solve<<<dim3(8, 8), 256, 0, stream>>>(ws);
    k_gemmE<<<512, 256, 0, stream>>>(ws, out);
}

// Round 17
// 2293.305 us; speedup vs baseline: 1.1331x; 1.0106x over previous
//
#include <hip/hip_runtime.h>

typedef unsigned int u32;
typedef unsigned long long u64;

#define NPTS  1024
#define DIMD  512
#define KCL   64
#define KMIT  10

// ---- workspace layout (element offsets, all 4-byte elems) ----
constexpr size_t O_CTG  = 0;                        // [64 runs][512 d][64 c]
constexpr size_t O_SUMS = O_CTG  + 64ull*512*64;    // [64][64 c][512 d] (reused: PS0, then CS)
constexpr size_t O_CNT  = O_SUMS + 64ull*64*512;    // [64][64] int
constexpr size_t O_SQC  = O_CNT  + 64ull*64;        // [64][64]
constexpr size_t O_SQP  = O_SQC  + 64ull*64;        // [64][1024]
constexpr size_t O_ASG  = O_SQP  + 64ull*1024;      // [64][1024] int
constexpr size_t O_CTN  = O_ASG  + 64ull*1024;      // [8 n][256 c][512 d]
constexpr size_t O_Y    = O_CTN  + 8ull*256*512;    // [8][4][4][64] int
constexpr size_t O_CNT2 = O_Y    + 8ull*4*4*64;     // [8][256] int
constexpr size_t O_BM   = O_CNT2 + 8ull*256;        // [8][256 c][512 d]
constexpr size_t O_G    = O_BM   + 8ull*256*512;    // [8][256][256]
constexpr size_t O_LT   = O_G    + 8ull*256*256;    // [8][256][256]  LT[a][b]=L[b][a]
constexpr size_t O_YB   = O_LT   + 8ull*256*256;    // [8][256][512] (reused: W/WT)
constexpr size_t O_ZB   = O_YB   + 8ull*256*512;    // [8][256][512]
constexpr size_t O_PTST = O_ZB   + 8ull*256*512;    // [64][1024 p][512 d]

// partial sums for kmeans (loop-phase only).
constexpr size_t O_PS0 = O_SUMS;                    // [64][64 c][512 d]
constexpr size_t O_PS1 = O_CTN;                     // [64][64 c][512 d]
static_assert(O_PS1 + 64ull*64*512 <= O_G, "PS1 overlay must fit before O_G");

// post-loop overlays:
constexpr size_t O_CS = O_SUMS;                     // [8 n][4 i][64 k][512 d] source centers rows
constexpr size_t O_W  = O_YB;                       // [8][4][64 r][64 k]  W = inv(L_ii)
constexpr size_t O_WT = O_YB + 8ull*4*64*64;        // [8][4][64 k][64 r]  W^T

__device__ __forceinline__ const float* run_base(const float* s, const float* t, int run){
    const float* b = (run < 32) ? s : t;
    return b + (size_t)(run & 31) * (DIMD * NPTS);
}
// monotonic pack of (d2, idx): min picks smallest d2, ties -> smallest idx (matches jnp.argmin)
__device__ __forceinline__ u64 dpack(float d2, int c){
    u32 u = __float_as_uint(d2);
    u = (u & 0x80000000u) ? ~u : (u | 0x80000000u);
    return ((u64)u << 32) | (u32)c;
}
__device__ __forceinline__ float rdlane(float v, int l){
    return __uint_as_float(__builtin_amdgcn_readlane(__float_as_uint(v), l));
}

// ---- init: sqp (per-point |p|^2), initial centers (first 64 pts), sqc, zero cnt ----
__global__ __launch_bounds__(256) void k_init(const float* __restrict__ src, const float* __restrict__ tgt,
                                              float* __restrict__ ws){
    int bx = blockIdx.x; int run = bx >> 2, q = bx & 3;
    int tid = threadIdx.x;
    const float* base = run_base(src, tgt, run);
    int p = q*256 + tid;
    float acc = 0.f;
    for (int d = 0; d < DIMD; ++d){
        float v = base[(size_t)d*NPTS + p];
        acc = fmaf(v, v, acc);
    }
    ws[O_SQP + run*NPTS + p] = acc;
    if (q == 0){
        if (tid < KCL) ws[O_SQC + run*KCL + tid] = acc;
        if (tid < KCL) ((int*)(ws + O_CNT))[run*KCL + tid] = 0;
        for (int idx = tid; idx < DIMD*KCL; idx += 256){
            int d = idx >> 6, c = idx & 63;
            ws[O_CTG + (size_t)run*DIMD*KCL + idx] = base[(size_t)d*NPTS + c];
        }
    }
}

// ---- build transposed points copy [run][p][d] for deterministic sums ----
__global__ __launch_bounds__(256) void k_ptsT(const float* __restrict__ src, const float* __restrict__ tgt,
                                              float* __restrict__ ws){
    int bx = blockIdx.x; int dt = bx & 7, pt = (bx >> 3) & 15, run = bx >> 7;
    int tid = threadIdx.x, lane = tid & 63, r4 = tid >> 6;
    const float* base = run_base(src, tgt, run);
    __shared__ float t[64*65];
    for (int pass = 0; pass < 16; ++pass){
        int r = pass*4 + r4;
        t[r*65 + lane] = base[(size_t)(dt*64 + r)*NPTS + pt*64 + lane];
    }
    __syncthreads();
    for (int pass = 0; pass < 16; ++pass){
        int p = pass*4 + r4;
        ws[O_PTST + ((size_t)run*NPTS + pt*64 + p)*DIMD + dt*64 + lane] = t[lane*65 + p];
    }
}

// ---- kmeans assignment: 512 blocks x 512 threads (8 waves, wave g owns 8 centers) ----
// Points read ONCE; asg/cnt written directly. Per-thread math identical to the
// proven 8-dim ping-pong structure (bit-identical assignments).
__global__ __launch_bounds__(512, 2) void k_assign(const float* __restrict__ src, const float* __restrict__ tgt,
                                                   const float* __restrict__ ctr, const float* __restrict__ sqc,
                                                   const float* __restrict__ sqp,
                                                   int* __restrict__ asg, int* __restrict__ cnt){
    int bxx = blockIdx.x;                    // 0..511
    int run = bxx >> 3, qt = bxx & 7;
    int tid = threadIdx.x, lane = tid & 63;
    int g = __builtin_amdgcn_readfirstlane(tid >> 6);   // wave 0..7
    int c0 = g*8;                            // this wave's 8 centers
    const float* base = run_base(src, tgt, run);
    const float* cg = ctr + (size_t)run*DIMD*KCL + c0;
    int p0 = qt*128 + 2*lane;                // points p0, p0+1
    float acc[2][8] = {};
    __shared__ u64 red[8][128];

#define LOADP(P, DB) { \
    _Pragma("unroll") \
    for (int u = 0; u < 8; ++u) \
        P[u] = *(const float2*)&base[(size_t)((DB)*8 + u)*NPTS + p0]; }

#define COMPUTE(P, DB) { \
    _Pragma("unroll") \
    for (int u = 0; u < 8; ++u){ \
        const float4* cp = (const float4*)(cg + (size_t)((DB)*8 + u)*KCL); \
        float4 c0v = cp[0], c1v = cp[1]; \
        float cv[8] = {c0v.x,c0v.y,c0v.z,c0v.w, c1v.x,c1v.y,c1v.z,c1v.w}; \
        _Pragma("unroll") \
        for (int cl = 0; cl < 8; ++cl){ \
            acc[0][cl] = fmaf(P[u].x, cv[cl], acc[0][cl]); \
            acc[1][cl] = fmaf(P[u].y, cv[cl], acc[1][cl]); \
        } \
    } }

    float2 pa[8], pb[8];
    LOADP(pa, 0);
    for (int db = 0; db < 64; db += 2){
        if (db + 1 < 64) LOADP(pb, db + 1);
        COMPUTE(pa, db);
        if (db + 2 < 64) LOADP(pa, db + 2);
        COMPUTE(pb, db + 1);
    }
#undef LOADP
#undef COMPUTE

    const float* sqcg = sqc + run*KCL + c0;
    float sq[8];
    #pragma unroll
    for (int q = 0; q < 8; ++q) sq[q] = sqcg[q];
    float2 sq2 = *(const float2*)&sqp[run*NPTS + p0];
    #pragma unroll
    for (int s = 0; s < 2; ++s){
        float sqpv = s ? sq2.y : sq2.x;
        u64 best = dpack(sqpv + sq[0] - 2.f*acc[s][0], c0);
        #pragma unroll
        for (int cl = 1; cl < 8; ++cl){
            u64 k2 = dpack(sqpv + sq[cl] - 2.f*acc[s][cl], c0 + cl);
            best = (k2 < best) ? k2 : best;
        }
        red[g][2*lane + s] = best;
    }
    __syncthreads();
    if (tid < 128){
        u64 b = red[0][tid];
        #pragma unroll
        for (int g2 = 1; g2 < 8; ++g2){ u64 k2 = red[g2][tid]; b = (k2 < b) ? k2 : b; }
        int c = (int)(b & 0xffffffffu);
        asg[run*NPTS + qt*128 + tid] = c;
        atomicAdd(&cnt[run*KCL + c], 1);
    }
}

// ---- kmeans partial sums: reads asg directly ----
__global__ __launch_bounds__(256) void k_sums(float* __restrict__ ws){
    int bx = blockIdx.x; int pg = bx & 1, dh = (bx >> 1) & 1, run = bx >> 2;
    int tid = threadIdx.x;
    __shared__ float sm[KCL*256];
    __shared__ int a[512];
    const int* asg = (const int*)(ws + O_ASG);
    for (int idx = tid; idx < 512; idx += 256) a[idx] = asg[run*NPTS + pg*512 + idx];
    for (int idx = tid; idx < KCL*256; idx += 256) sm[idx] = 0.f;
    __syncthreads();
    const float* pT = ws + O_PTST + ((size_t)run*NPTS + pg*512)*DIMD + dh*256 + tid;
    for (int p = 0; p < 512; p += 4){
        float v0 = pT[(size_t)(p+0)*DIMD], v1 = pT[(size_t)(p+1)*DIMD];
        float v2 = pT[(size_t)(p+2)*DIMD], v3 = pT[(size_t)(p+3)*DIMD];
        sm[a[p+0]*256 + tid] += v0;
        sm[a[p+1]*256 + tid] += v1;
        sm[a[p+2]*256 + tid] += v2;
        sm[a[p+3]*256 + tid] += v3;
    }
    __syncthreads();
    size_t psx = pg ? O_PS1 : O_PS0;
    for (int c = 0; c < KCL; ++c)
        ws[psx + ((size_t)run*KCL + c)*DIMD + dh*256 + tid] = sm[c*256 + tid];
}

// ---- kmeans center update + sqc + zero cnt (deterministic: ps0+ps1) ----
__global__ __launch_bounds__(256) void k_newc(float* __restrict__ ws){
    int run = blockIdx.x, tid = threadIdx.x;
    __shared__ float sm2[KCL*65];
    __shared__ int cl[KCL];
    int* cnt = (int*)(ws + O_CNT);
    if (tid < KCL) cl[tid] = cnt[run*KCL + tid];
    __syncthreads();
    if (tid < KCL) cnt[run*KCL + tid] = 0;
    float sqa = 0.f;
    for (int dc = 0; dc < 8; ++dc){
        for (int idx = tid; idx < KCL*64; idx += 256){
            int c = idx >> 6, dl = idx & 63;
            size_t o = ((size_t)run*KCL + c)*DIMD + dc*64 + dl;
            sm2[c*65 + dl] = ws[O_PS0 + o] + ws[O_PS1 + o];
        }
        __syncthreads();
        for (int idx = tid; idx < KCL*64; idx += 256){
            int dl = idx >> 6, c = idx & 63, d = dc*64 + dl;
            size_t gi = O_CTG + (size_t)run*DIMD*KCL + d*KCL + c;
            float old = ws[gi];
            int cc = cl[c];
            float nv = (cc > 0) ? sm2[c*65 + dl] / (float)cc : old;
            ws[gi] = nv;
            sm2[c*65 + dl] = nv;
        }
        __syncthreads();
        if (tid < KCL){
            for (int dl = 0; dl < 64; ++dl){ float v = sm2[tid*65 + dl]; sqa = fmaf(v, v, sqa); }
        }
        __syncthreads();
    }
    if (tid < KCL) ws[O_SQC + run*KCL + tid] = sqa;
}

// ---- regroup centers to row-major: target -> CTN [n][256c][512d]; source -> CS [n][4i][64k][512d] ----
__global__ __launch_bounds__(256) void k_ctn(float* __restrict__ ws){
    int bx = blockIdx.x; int dc = bx & 7, jj = (bx >> 3) & 3, n = (bx >> 5) & 7, st = bx >> 8;
    int run = st ? (jj*8 + n) : (32 + jj*8 + n);
    int tid = threadIdx.x, lane = tid & 63, r4 = tid >> 6;
    __shared__ float t[64*65];
    for (int pass = 0; pass < 16; ++pass){
        int r = pass*4 + r4;
        t[r*65 + lane] = ws[O_CTG + (size_t)run*DIMD*KCL + (dc*64 + r)*KCL + lane];
    }
    __syncthreads();
    size_t dstbase = st ? (O_CS  + ((size_t)(n*4 + jj)*64)*DIMD)
                        : (O_CTN + ((size_t)n*256 + jj*64)*DIMD);
    for (int pass = 0; pass < 16; ++pass){
        int l = pass*4 + r4;
        ws[dstbase + (size_t)l*DIMD + dc*64 + lane] = t[lane*65 + l];
    }
}

// ---- source->target center matching ----
__global__ __launch_bounds__(256) void k_map(float* __restrict__ ws){
    int bx = blockIdx.x; int j = bx & 3, i = (bx >> 2) & 3, n = bx >> 4;
    int run_s = i*8 + n, run_t = 32 + j*8 + n;
    int tid = threadIdx.x, lane = tid & 63;
    int g = __builtin_amdgcn_readfirstlane(tid >> 6);
    const float* cgs = ws + O_CTG + (size_t)run_s*DIMD*KCL + lane;
    const float* cgt = ws + O_CTG + (size_t)run_t*DIMD*KCL + g*16;
    float acc[16] = {};
    for (int d = 0; d < DIMD; ++d){
        float csv = cgs[d*KCL];
        const float4* cp = (const float4*)(cgt + d*KCL);
        float4 c0=cp[0], c1=cp[1], c2=cp[2], c3=cp[3];
        float cv[16] = {c0.x,c0.y,c0.z,c0.w, c1.x,c1.y,c1.z,c1.w,
                        c2.x,c2.y,c2.z,c2.w, c3.x,c3.y,c3.z,c3.w};
        #pragma unroll
        for (int cl = 0; cl < 16; ++cl) acc[cl] = fmaf(csv, cv[cl], acc[cl]);
    }
    float sqs = ws[O_SQC + run_s*KCL + lane];
    const float* sqtp = ws + O_SQC + run_t*KCL + g*16;
    u64 best = dpack(sqs + sqtp[0] - 2.f*acc[0], g*16);
    #pragma unroll
    for (int cl = 1; cl < 16; ++cl){
        u64 k2 = dpack(sqs + sqtp[cl] - 2.f*acc[cl], g*16 + cl);
        best = (k2 < best) ? k2 : best;
    }
    __shared__ u64 red[4][64];
    red[g][lane] = best;
    __syncthreads();
    if (tid < 64){
        u64 b = red[0][tid];
        #pragma unroll
        for (int g2 = 1; g2 < 4; ++g2){ u64 k2 = red[g2][tid]; b = (k2 < b) ? k2 : b; }
        int l = (int)(b & 0xffffffffu);
        int* yv   = (int*)(ws + O_Y);
        int* cnt2 = (int*)(ws + O_CNT2);
        yv[((n*4 + i)*4 + j)*64 + tid] = l;
        atomicAdd(&cnt2[n*256 + j*64 + l], 1);
    }
}

// ---- B matrix: serial gather-accumulate over 256 sources, coalesced rows, no atomics ----
__global__ __launch_bounds__(256) void k_bmat(float* __restrict__ ws){
    int bx = blockIdx.x; int dh = bx & 1, j = (bx >> 1) & 3, n = bx >> 3;
    int tid = threadIdx.x;
    __shared__ float Bacc[KCL*256];   // 64 KB
    __shared__ int yl[256];
    __shared__ int c2[KCL];
    const int* yv   = (const int*)(ws + O_Y);
    const int* cnt2 = (const int*)(ws + O_CNT2);
    { int i = tid >> 6, k = tid & 63; yl[tid] = yv[((n*4 + i)*4 + j)*64 + k]; }
    if (tid < KCL) c2[tid] = cnt2[n*256 + j*64 + tid];
    for (int idx = tid; idx < KCL*256; idx += 256) Bacc[idx] = 0.f;
    __syncthreads();
    const float* cs = ws + O_CS + (size_t)(n*4)*64*DIMD + dh*256 + tid;
    #pragma unroll 4
    for (int s = 0; s < 256; ++s){
        int l = yl[s];
        float v = cs[(size_t)s*DIMD];
        Bacc[l*256 + tid] += v;
    }
    __syncthreads();
    for (int l = 0; l < KCL; ++l){
        int cc = c2[l]; if (cc < 1) cc = 1;
        ws[O_BM + ((size_t)n*256 + j*64 + l)*DIMD + dh*256 + tid] = Bacc[l*256 + tid] / (float)cc;
    }
}

// ---- masked Gram: tiled A·A^T over CTN rows (coalesced, L2-friendly) ----
__global__ __launch_bounds__(256) void k_gram(float* __restrict__ ws){
    int bx = blockIdx.x; int ti = bx & 3, tj = (bx >> 2) & 3, n = bx >> 4;
    int tid = threadIdx.x;
    int tx = tid & 15, ty = tid >> 4;
    const float* A = ws + O_CTN + (size_t)n*256*DIMD;
    __shared__ __align__(16) float Ai[64*65];
    __shared__ __align__(16) float Aj[64*65];
    float acc[4][4] = {};
    for (int kc = 0; kc < 8; ++kc){
        __syncthreads();
        for (int idx = tid; idx < 1024; idx += 256){
            int r = idx >> 4, c4 = idx & 15;
            *(float4*)&Ai[r*65 + c4*4] = *(const float4*)&A[(size_t)(ti*64 + r)*DIMD + kc*64 + c4*4];
            *(float4*)&Aj[r*65 + c4*4] = *(const float4*)&A[(size_t)(tj*64 + r)*DIMD + kc*64 + c4*4];
        }
        __syncthreads();
        #pragma unroll 8
        for (int k = 0; k < 64; ++k){
            float ar[4], br[4];
            #pragma unroll
            for (int a = 0; a < 4; ++a) ar[a] = Ai[(ty*4 + a)*65 + k];
            #pragma unroll
            for (int b = 0; b < 4; ++b) br[b] = Aj[(tx*4 + b)*65 + k];
            #pragma unroll
            for (int a = 0; a < 4; ++a)
                #pragma unroll
                for (int b = 0; b < 4; ++b)
                    acc[a][b] = fmaf(ar[a], br[b], acc[a][b]);
        }
    }
    const int* cnt2 = (const int*)(ws + O_CNT2);
    float* Gp = ws + O_G + (size_t)n*65536;
    #pragma unroll
    for (int a = 0; a < 4; ++a){
        int row = ti*64 + ty*4 + a;
        bool ur = cnt2[n*256 + row] > 0;
        #pragma unroll
        for (int b = 0; b < 4; ++b){
            int col = tj*64 + tx*4 + b;
            bool uc = cnt2[n*256 + col] > 0;
            float v = (ur && uc) ? acc[a][b] : ((row == col) ? 1.f : 0.f);
            Gp[(size_t)row*256 + col] = v;
        }
    }
}

// ---- Cholesky panel: register-lockstep fused diag factor + panel solve (one kb) ----
__global__ __launch_bounds__(256, 1) void k_cholp(float* __restrict__ ws, int kb){
    int n = blockIdx.x, tid = threadIdx.x;
    int lane = tid & 63, wv = tid >> 6;
    float* Gn  = ws + O_G  + (size_t)n*65536;
    float* LTn = ws + O_LT + (size_t)n*65536;
    int c0 = kb*64, r1 = c0 + 64, rem = 256 - r1;

    float dreg[64];
    {
        const float* grow = Gn + (size_t)(c0+lane)*256 + c0;
        #pragma unroll
        for (int j4 = 0; j4 < 16; ++j4){
            float4 v = *(const float4*)&grow[j4*4];
            dreg[j4*4+0]=v.x; dreg[j4*4+1]=v.y; dreg[j4*4+2]=v.z; dreg[j4*4+3]=v.w;
        }
    }
    float preg[64];
    int prow = (wv-1)*64 + lane;
    bool pact = (wv >= 1) && (prow < rem);
    {
        const float* growp = Gn + (size_t)(r1+prow)*256 + c0;
        #pragma unroll
        for (int j4 = 0; j4 < 16; ++j4){
            if (pact){
                float4 v = *(const float4*)&growp[j4*4];
                preg[j4*4+0]=v.x; preg[j4*4+1]=v.y; preg[j4*4+2]=v.z; preg[j4*4+3]=v.w;
            } else {
                preg[j4*4+0]=0.f; preg[j4*4+1]=0.f; preg[j4*4+2]=0.f; preg[j4*4+3]=0.f;
            }
        }
    }
    #pragma unroll
    for (int k = 0; k < 64; ++k){
        float dkk = sqrtf(fmaxf(rdlane(dreg[k], k), 1e-30f));
        float inv = 1.f / dkk;
        dreg[k] = (lane == k) ? dkk : dreg[k]*inv;
        preg[k] *= inv;
        #pragma unroll
        for (int j = k+1; j < 64; ++j){
            float s = rdlane(dreg[k], j);
            dreg[j] = fmaf(-dreg[k], s, dreg[j]);
            preg[j] = fmaf(-preg[k], s, preg[j]);
        }
    }
    if (wv == 0){
        float* grow = Gn + (size_t)(c0+lane)*256 + c0;
        #pragma unroll
        for (int j4 = 0; j4 < 16; ++j4){
            float4 v; v.x=dreg[j4*4+0]; v.y=dreg[j4*4+1]; v.z=dreg[j4*4+2]; v.w=dreg[j4*4+3];
            *(float4*)&grow[j4*4] = v;
        }
    }
    if (pact){
        float* growp = Gn + (size_t)(r1+prow)*256 + c0;
        #pragma unroll
        for (int j4 = 0; j4 < 16; ++j4){
            float4 v; v.x=preg[j4*4+0]; v.y=preg[j4*4+1]; v.z=preg[j4*4+2]; v.w=preg[j4*4+3];
            *(float4*)&growp[j4*4] = v;
        }
        float* ltp = LTn + (size_t)c0*256 + r1 + prow;
        #pragma unroll
        for (int j = 0; j < 64; ++j) ltp[(size_t)j*256] = preg[j];
    }
}

// ---- trailing update for panel kb, wide-parallel: C -= Lp * Lp^T (lower 4x4 tiles) ----
__global__ __launch_bounds__(256) void k_trail(float* __restrict__ ws, int kb){
    int n = blockIdx.y;
    int c0 = kb*64, r1 = c0 + 64, rem = 256 - r1;
    int nt4 = rem >> 2;
    int ntiles = nt4*(nt4+1)/2;
    float* Gn = ws + O_G + (size_t)n*65536;
    for (int t = blockIdx.x*256 + threadIdx.x; t < ntiles; t += gridDim.x*256){
        int ti = (int)((sqrtf(8.f*(float)t + 1.f) - 1.f) * 0.5f);
        while ((ti+1)*(ti+2)/2 <= t) ++ti;
        while (ti*(ti+1)/2 > t) --ti;
        int tj = t - ti*(ti+1)/2;
        int i0 = ti*4, j0 = tj*4;
        const float* Li = Gn + (size_t)(r1+i0)*256 + c0;
        const float* Lj = Gn + (size_t)(r1+j0)*256 + c0;
        float acc[4][4] = {};
        for (int k = 0; k < 64; k += 4){
            float4 ar4[4], br4[4];
            #pragma unroll
            for (int r = 0; r < 4; ++r) ar4[r] = *(const float4*)&Li[(size_t)r*256 + k];
            #pragma unroll
            for (int s = 0; s < 4; ++s) br4[s] = *(const float4*)&Lj[(size_t)s*256 + k];
            #pragma unroll
            for (int q = 0; q < 4; ++q){
                float aq[4] = { q==0?ar4[0].x:q==1?ar4[0].y:q==2?ar4[0].z:ar4[0].w,
                                q==0?ar4[1].x:q==1?ar4[1].y:q==2?ar4[1].z:ar4[1].w,
                                q==0?ar4[2].x:q==1?ar4[2].y:q==2?ar4[2].z:ar4[2].w,
                                q==0?ar4[3].x:q==1?ar4[3].y:q==2?ar4[3].z:ar4[3].w };
                float bq[4] = { q==0?br4[0].x:q==1?br4[0].y:q==2?br4[0].z:br4[0].w,
                                q==0?br4[1].x:q==1?br4[1].y:q==2?br4[1].z:br4[1].w,
                                q==0?br4[2].x:q==1?br4[2].y:q==2?br4[2].z:br4[2].w,
                                q==0?br4[3].x:q==1?br4[3].y:q==2?br4[3].z:br4[3].w };
                #pragma unroll
                for (int r = 0; r < 4; ++r)
                    #pragma unroll
                    for (int s = 0; s < 4; ++s)
                        acc[r][s] = fmaf(aq[r], bq[s], acc[r][s]);
            }
        }
        #pragma unroll
        for (int r = 0; r < 4; ++r){
            float* grow = Gn + (size_t)(r1+i0+r)*256 + r1 + j0;
            #pragma unroll
            for (int s = 0; s < 4; ++s) grow[s] -= acc[r][s];
        }
    }
}

// ---- diag-block inverses: W_i = inv(L_ii), column-parallel per lane ----
__global__ __launch_bounds__(256, 1) void k_dinv(float* __restrict__ ws){
    int n = blockIdx.x, tid = threadIdx.x;
    int lane = tid & 63, kb = tid >> 6;
    const float* Gn = ws + O_G + (size_t)n*65536;
    __shared__ __align__(16) float DlT[4][64*65];   // DlT[kb][k*65+i] = L[i][k]
    for (int idx = lane; idx < 1024; idx += 64){
        int r = idx >> 4, c4 = idx & 15;
        float4 v = *(const float4*)&Gn[(size_t)(kb*64 + r)*256 + kb*64 + c4*4];
        DlT[kb][(c4*4+0)*65 + r] = v.x;
        DlT[kb][(c4*4+1)*65 + r] = v.y;
        DlT[kb][(c4*4+2)*65 + r] = v.z;
        DlT[kb][(c4*4+3)*65 + r] = v.w;
    }
    __syncthreads();
    float x[64];
    #pragma unroll
    for (int i = 0; i < 64; ++i) x[i] = (i == lane) ? 1.f : 0.f;
    const float* Dk = DlT[kb];
    #pragma unroll
    for (int k = 0; k < 64; ++k){
        float invd = 1.f / Dk[k*65 + k];
        x[k] *= invd;
        #pragma unroll
        for (int i = k+1; i < 64; ++i)
            x[i] = fmaf(-Dk[k*65 + i], x[k], x[i]);
    }
    float* Wg  = ws + O_W  + ((size_t)n*4 + kb)*4096;
    float* WTg = ws + O_WT + ((size_t)n*4 + kb)*4096;
    #pragma unroll
    for (int r = 0; r < 64; ++r) Wg[r*64 + lane] = x[r];
    #pragma unroll
    for (int r4 = 0; r4 < 16; ++r4){
        float4 v; v.x=x[r4*4+0]; v.y=x[r4*4+1]; v.z=x[r4*4+2]; v.w=x[r4*4+3];
        *(float4*)&WTg[lane*64 + r4*4] = v;
    }
}

// ---- triangular solves as block GEMMs: G Z = Ct via L Y = Ct; L^T Z = Y ----
__global__ __launch_bounds__(256, 1) void k_solve(float* __restrict__ ws){
    int n = blockIdx.x, cg = blockIdx.y;
    int tid = threadIdx.x;
    int tx = tid & 15, ty = tid >> 4;
    const float* Gn  = ws + O_G  + (size_t)n*65536;
    const float* LTn = ws + O_LT + (size_t)n*65536;
    const float* Ct  = ws + O_CTN + (size_t)n*256*DIMD + (size_t)cg*64;
    const float* Wg  = ws + O_W  + (size_t)n*4*4096;
    const float* WTg = ws + O_WT + (size_t)n*4*4096;
    float* Zb = ws + O_ZB + (size_t)n*256*DIMD + (size_t)cg*64;

    __shared__ __align__(16) float YL[4][64*65];
    __shared__ __align__(16) float At[64*65];
    __shared__ __align__(16) float RL[64*65];

    float acc[4][4];
    for (int bi = 0; bi < 4; ++bi){
        #pragma unroll
        for (int a = 0; a < 4; ++a){
            float4 v = *(const float4*)&Ct[(size_t)(bi*64 + ty*4 + a)*DIMD + tx*4];
            acc[a][0]=v.x; acc[a][1]=v.y; acc[a][2]=v.z; acc[a][3]=v.w;
        }
        for (int j = 0; j < bi; ++j){
            __syncthreads();
            for (int idx = tid; idx < 1024; idx += 256){
                int k = idx >> 4, r4 = idx & 15;
                float4 v = *(const float4*)&LTn[(size_t)(j*64 + k)*256 + bi*64 + r4*4];
                *(float4*)&At[k*65 + r4*4] = v;
            }
            __syncthreads();
            const float* Yj = YL[j];
            #pragma unroll 8
            for (int k = 0; k < 64; ++k){
                float4 av = *(const float4*)&At[k*65 + ty*4];
                float4 yv = *(const float4*)&Yj[k*65 + tx*4];
                float ar[4] = {av.x,av.y,av.z,av.w};
                float yr[4] = {yv.x,yv.y,yv.z,yv.w};
                #pragma unroll
                for (int a = 0; a < 4; ++a)
                    #pragma unroll
                    for (int b = 0; b < 4; ++b)
                        acc[a][b] = fmaf(-ar[a], yr[b], acc[a][b]);
            }
        }
        __syncthreads();
        #pragma unroll
        for (int a = 0; a < 4; ++a){
            float4 v; v.x=acc[a][0]; v.y=acc[a][1]; v.z=acc[a][2]; v.w=acc[a][3];
            *(float4*)&RL[(ty*4 + a)*65 + tx*4] = v;
        }
        for (int idx = tid; idx < 1024; idx += 256){
            int k = idx >> 4, r4 = idx & 15;
            float4 v = *(const float4*)&WTg[(size_t)bi*4096 + k*64 + r4*4];
            *(float4*)&At[k*65 + r4*4] = v;
        }
        __syncthreads();
        float out[4][4] = {};
        #pragma unroll 8
        for (int k = 0; k < 64; ++k){
            float4 av = *(const float4*)&At[k*65 + ty*4];
            float4 rv = *(const float4*)&RL[k*65 + tx*4];
            float ar[4] = {av.x,av.y,av.z,av.w};
            float rr[4] = {rv.x,rv.y,rv.z,rv.w};
            #pragma unroll
            for (int a = 0; a < 4; ++a)
                #pragma unroll
                for (int b = 0; b < 4; ++b)
                    out[a][b] = fmaf(ar[a], rr[b], out[a][b]);
        }
        float* Yi = YL[bi];
        #pragma unroll
        for (int a = 0; a < 4; ++a){
            float4 v; v.x=out[a][0]; v.y=out[a][1]; v.z=out[a][2]; v.w=out[a][3];
            *(float4*)&Yi[(ty*4 + a)*65 + tx*4] = v;
        }
    }
    for (int bi = 3; bi >= 0; --bi){
        __syncthreads();
        #pragma unroll
        for (int a = 0; a < 4; ++a){
            float4 v = *(const float4*)&YL[bi][(ty*4 + a)*65 + tx*4];
            acc[a][0]=v.x; acc[a][1]=v.y; acc[a][2]=v.z; acc[a][3]=v.w;
        }
        for (int j = bi+1; j < 4; ++j){
            __syncthreads();
            for (int idx = tid; idx < 1024; idx += 256){
                int k = idx >> 4, r4 = idx & 15;
                float4 v = *(const float4*)&Gn[(size_t)(j*64 + k)*256 + bi*64 + r4*4];
                *(float4*)&At[k*65 + r4*4] = v;
            }
            __syncthreads();
            const float* Zj = YL[j];
            #pragma unroll 8
            for (int k = 0; k < 64; ++k){
                float4 av = *(const float4*)&At[k*65 + ty*4];
                float4 zv = *(const float4*)&Zj[k*65 + tx*4];
                float ar[4] = {av.x,av.y,av.z,av.w};
                float zr[4] = {zv.x,zv.y,zv.z,zv.w};
                #pragma unroll
                for (int a = 0; a < 4; ++a)
                    #pragma unroll
                    for (int b = 0; b < 4; ++b)
                        acc[a][b] = fmaf(-ar[a], zr[b], acc[a][b]);
            }
        }
        __syncthreads();
        #pragma unroll
        for (int a = 0; a < 4; ++a){
            float4 v; v.x=acc[a][0]; v.y=acc[a][1]; v.z=acc[a][2]; v.w=acc[a][3];
            *(float4*)&RL[(ty*4 + a)*65 + tx*4] = v;
        }
        for (int idx = tid; idx < 1024; idx += 256){
            int k = idx >> 4, r4 = idx & 15;
            float4 v = *(const float4*)&Wg[(size_t)bi*4096 + k*64 + r4*4];
            *(float4*)&At[k*65 + r4*4] = v;
        }
        __syncthreads();
        float out[4][4] = {};
        #pragma unroll 8
        for (int k = 0; k < 64; ++k){
            float4 av = *(const float4*)&At[k*65 + ty*4];
            float4 rv = *(const float4*)&RL[k*65 + tx*4];
            float ar[4] = {av.x,av.y,av.z,av.w};
            float rr[4] = {rv.x,rv.y,rv.z,rv.w};
            #pragma unroll
            for (int a = 0; a < 4; ++a)
                #pragma unroll
                for (int b = 0; b < 4; ++b)
                    out[a][b] = fmaf(ar[a], rr[b], out[a][b]);
        }
        float* Zi = YL[bi];
        #pragma unroll
        for (int a = 0; a < 4; ++a){
            float4 v; v.x=out[a][0]; v.y=out[a][1]; v.z=out[a][2]; v.w=out[a][3];
            *(float4*)&Zi[(ty*4 + a)*65 + tx*4] = v;
            *(float4*)&Zb[(size_t)(bi*64 + ty*4 + a)*DIMD + tx*4] = v;
        }
    }
}

// ---- final GEMM: trans[d][e] = sum_c Bm[c][d] * Z[c][e] ----
__global__ __launch_bounds__(256) void k_gemmE(const float* __restrict__ ws, float* __restrict__ out){
    int bx = blockIdx.x; int et = bx & 7, dt = (bx >> 3) & 7, n = bx >> 6;
    int tid = threadIdx.x;
    __shared__ float Bl[256*64];
    __shared__ float Zl[256*64];
    const float* Bm = ws + O_BM + (size_t)n*256*DIMD;
    const float* Zb = ws + O_ZB + (size_t)n*256*DIMD;
    for (int idx = tid; idx < 16384; idx += 256){
        int c = idx >> 6, dd = idx & 63;
        Bl[idx] = Bm[(size_t)c*DIMD + dt*64 + dd];
        Zl[idx] = Zb[(size_t)c*DIMD + et*64 + dd];
    }
    __syncthreads();
    int td = tid & 15, te = tid >> 4;
    float acc[4][4] = {};
    for (int c = 0; c < 256; ++c){
        float4 bv = *(const float4*)&Bl[c*64 + td*4];
        float4 zv = *(const float4*)&Zl[c*64 + te*4];
        float b4[4] = {bv.x, bv.y, bv.z, bv.w};
        float z4[4] = {zv.x, zv.y, zv.z, zv.w};
        #pragma unroll
        for (int r = 0; r < 4; ++r)
            #pragma unroll
            for (int s = 0; s < 4; ++s) acc[r][s] = fmaf(b4[r], z4[s], acc[r][s]);
    }
    float* ob = out + (size_t)n*262144 + (size_t)(dt*64 + td*4)*DIMD + et*64 + te*4;
    #pragma unroll
    for (int r = 0; r < 4; ++r){
        float4 o; o.x = acc[r][0]; o.y = acc[r][1]; o.z = acc[r][2]; o.w = acc[r][3];
        *(float4*)&ob[(size_t)r*DIMD] = o;
    }
}

extern "C" void kernel_launch(void* const* d_in, const int* in_sizes, int n_in,
                              void* d_out, int out_size, void* d_ws, size_t ws_size,
                              hipStream_t stream){
    const float* src = (const float*)d_in[0];
    const float* tgt = (const float*)d_in[1];
    float* ws  = (float*)d_ws;
    float* out = (float*)d_out;

    k_init<<<256, 256, 0, stream>>>(src, tgt, ws);
    k_ptsT<<<8192, 256, 0, stream>>>(src, tgt, ws);

    for (int it = 0; it < KMIT; ++it){
        k_assign<<<512, 512, 0, stream>>>(src, tgt,
                                          ws + O_CTG, ws + O_SQC, ws + O_SQP,
                                          (int*)(ws + O_ASG), (int*)(ws + O_CNT));
        k_sums<<<256, 256, 0, stream>>>(ws);
        k_newc<<<64, 256, 0, stream>>>(ws);
    }

    hipMemsetAsync((char*)d_ws + O_CNT2*4, 0, 8*256*4, stream);
    k_ctn<<<512, 256, 0, stream>>>(ws);
    k_map<<<128, 256, 0, stream>>>(ws);
    k_bmat<<<64, 256, 0, stream>>>(ws);
    k_gram<<<128, 256, 0, stream>>>(ws);
    for (int kb = 0; kb < 4; ++kb){
        k_cholp<<<8, 256, 0, stream>>>(ws, kb);
        if (kb < 3) k_trail<<<dim3(8, 8), 256, 0, stream>>>(ws, kb);
    }
    k_dinv<<<8, 256, 0, stream>>>(ws);
    k_solve<<<dim3(8, 8), 256, 0, stream>>>(ws);
    k_gemmE<<<512, 256, 0, stream>>>(ws, out);
}

// Round 18
// 2183.580 us; speedup vs baseline: 1.1900x; 1.0503x over previous
//
#include <hip/hip_runtime.h>

typedef unsigned int u32;
typedef unsigned long long u64;

#define NPTS  1024
#define DIMD  512
#define KCL   64
#define KMIT  10

// ---- workspace layout (element offsets, all 4-byte elems) ----
constexpr size_t O_CTG  = 0;                        // [64 runs][512 d][64 c]
constexpr size_t O_SUMS = O_CTG  + 64ull*512*64;    // [64][64 c][512 d] (reused: PS0, then CS)
constexpr size_t O_CNT  = O_SUMS + 64ull*64*512;    // [64][64] int
constexpr size_t O_SQC  = O_CNT  + 64ull*64;        // [64][64]
constexpr size_t O_SQP  = O_SQC  + 64ull*64;        // [64][1024]
constexpr size_t O_ASG  = O_SQP  + 64ull*1024;      // [64][1024] int
constexpr size_t O_CTN  = O_ASG  + 64ull*1024;      // [8 n][256 c][512 d]
constexpr size_t O_Y    = O_CTN  + 8ull*256*512;    // [8][4][4][64] int
constexpr size_t O_CNT2 = O_Y    + 8ull*4*4*64;     // [8][256] int
constexpr size_t O_BM   = O_CNT2 + 8ull*256;        // [8][256 c][512 d]
constexpr size_t O_G    = O_BM   + 8ull*256*512;    // [8][256][256]
constexpr size_t O_LT   = O_G    + 8ull*256*256;    // [8][256][256]  LT[a][b]=L[b][a]
constexpr size_t O_YB   = O_LT   + 8ull*256*256;    // [8][256][512] (reused: W/WT)
constexpr size_t O_ZB   = O_YB   + 8ull*256*512;    // [8][256][512]
constexpr size_t O_PTST = O_ZB   + 8ull*256*512;    // [64][1024 p][512 d]

// partial sums for kmeans (loop-phase only).
constexpr size_t O_PS0 = O_SUMS;                    // [64][64 c][512 d]
constexpr size_t O_PS1 = O_CTN;                     // [64][64 c][512 d]
static_assert(O_PS1 + 64ull*64*512 <= O_G, "PS1 overlay must fit before O_G");

// post-loop overlays:
constexpr size_t O_CS = O_SUMS;                     // [8 n][4 i][64 k][512 d] source centers rows
constexpr size_t O_W  = O_YB;                       // [8][4][64 r][64 k]  W = inv(L_ii)
constexpr size_t O_WT = O_YB + 8ull*4*64*64;        // [8][4][64 k][64 r]  W^T

__device__ __forceinline__ const float* run_base(const float* s, const float* t, int run){
    const float* b = (run < 32) ? s : t;
    return b + (size_t)(run & 31) * (DIMD * NPTS);
}
// monotonic pack of (d2, idx): min picks smallest d2, ties -> smallest idx (matches jnp.argmin)
__device__ __forceinline__ u64 dpack(float d2, int c){
    u32 u = __float_as_uint(d2);
    u = (u & 0x80000000u) ? ~u : (u | 0x80000000u);
    return ((u64)u << 32) | (u32)c;
}
__device__ __forceinline__ float rdlane(float v, int l){
    return __uint_as_float(__builtin_amdgcn_readlane(__float_as_uint(v), l));
}

// ---- init: sqp (per-point |p|^2), initial centers (first 64 pts), sqc, zero cnt ----
__global__ __launch_bounds__(256) void k_init(const float* __restrict__ src, const float* __restrict__ tgt,
                                              float* __restrict__ ws){
    int bx = blockIdx.x; int run = bx >> 2, q = bx & 3;
    int tid = threadIdx.x;
    const float* base = run_base(src, tgt, run);
    int p = q*256 + tid;
    float acc = 0.f;
    for (int d = 0; d < DIMD; ++d){
        float v = base[(size_t)d*NPTS + p];
        acc = fmaf(v, v, acc);
    }
    ws[O_SQP + run*NPTS + p] = acc;
    if (q == 0){
        if (tid < KCL) ws[O_SQC + run*KCL + tid] = acc;
        if (tid < KCL) ((int*)(ws + O_CNT))[run*KCL + tid] = 0;
        for (int idx = tid; idx < DIMD*KCL; idx += 256){
            int d = idx >> 6, c = idx & 63;
            ws[O_CTG + (size_t)run*DIMD*KCL + idx] = base[(size_t)d*NPTS + c];
        }
    }
}

// ---- build transposed points copy [run][p][d] for deterministic sums ----
__global__ __launch_bounds__(256) void k_ptsT(const float* __restrict__ src, const float* __restrict__ tgt,
                                              float* __restrict__ ws){
    int bx = blockIdx.x; int dt = bx & 7, pt = (bx >> 3) & 15, run = bx >> 7;
    int tid = threadIdx.x, lane = tid & 63, r4 = tid >> 6;
    const float* base = run_base(src, tgt, run);
    __shared__ float t[64*65];
    for (int pass = 0; pass < 16; ++pass){
        int r = pass*4 + r4;
        t[r*65 + lane] = base[(size_t)(dt*64 + r)*NPTS + pt*64 + lane];
    }
    __syncthreads();
    for (int pass = 0; pass < 16; ++pass){
        int p = pass*4 + r4;
        ws[O_PTST + ((size_t)run*NPTS + pt*64 + p)*DIMD + dt*64 + lane] = t[lane*65 + p];
    }
}

// ---- kmeans assignment: 512 blocks x 512 threads (8 waves, wave g owns 8 centers) ----
__global__ __launch_bounds__(512, 2) void k_assign(const float* __restrict__ src, const float* __restrict__ tgt,
                                                   const float* __restrict__ ctr, const float* __restrict__ sqc,
                                                   const float* __restrict__ sqp,
                                                   int* __restrict__ asg, int* __restrict__ cnt){
    int bxx = blockIdx.x;                    // 0..511
    int run = bxx >> 3, qt = bxx & 7;
    int tid = threadIdx.x, lane = tid & 63;
    int g = __builtin_amdgcn_readfirstlane(tid >> 6);   // wave 0..7
    int c0 = g*8;                            // this wave's 8 centers
    const float* base = run_base(src, tgt, run);
    const float* cg = ctr + (size_t)run*DIMD*KCL + c0;
    int p0 = qt*128 + 2*lane;                // points p0, p0+1
    float acc[2][8] = {};
    __shared__ u64 red[8][128];

#define LOADP(P, DB) { \
    _Pragma("unroll") \
    for (int u = 0; u < 8; ++u) \
        P[u] = *(const float2*)&base[(size_t)((DB)*8 + u)*NPTS + p0]; }

#define COMPUTE(P, DB) { \
    _Pragma("unroll") \
    for (int u = 0; u < 8; ++u){ \
        const float4* cp = (const float4*)(cg + (size_t)((DB)*8 + u)*KCL); \
        float4 c0v = cp[0], c1v = cp[1]; \
        float cv[8] = {c0v.x,c0v.y,c0v.z,c0v.w, c1v.x,c1v.y,c1v.z,c1v.w}; \
        _Pragma("unroll") \
        for (int cl = 0; cl < 8; ++cl){ \
            acc[0][cl] = fmaf(P[u].x, cv[cl], acc[0][cl]); \
            acc[1][cl] = fmaf(P[u].y, cv[cl], acc[1][cl]); \
        } \
    } }

    float2 pa[8], pb[8];
    LOADP(pa, 0);
    for (int db = 0; db < 64; db += 2){
        if (db + 1 < 64) LOADP(pb, db + 1);
        COMPUTE(pa, db);
        if (db + 2 < 64) LOADP(pa, db + 2);
        COMPUTE(pb, db + 1);
    }
#undef LOADP
#undef COMPUTE

    const float* sqcg = sqc + run*KCL + c0;
    float sq[8];
    #pragma unroll
    for (int q = 0; q < 8; ++q) sq[q] = sqcg[q];
    float2 sq2 = *(const float2*)&sqp[run*NPTS + p0];
    #pragma unroll
    for (int s = 0; s < 2; ++s){
        float sqpv = s ? sq2.y : sq2.x;
        u64 best = dpack(sqpv + sq[0] - 2.f*acc[s][0], c0);
        #pragma unroll
        for (int cl = 1; cl < 8; ++cl){
            u64 k2 = dpack(sqpv + sq[cl] - 2.f*acc[s][cl], c0 + cl);
            best = (k2 < best) ? k2 : best;
        }
        red[g][2*lane + s] = best;
    }
    __syncthreads();
    if (tid < 128){
        u64 b = red[0][tid];
        #pragma unroll
        for (int g2 = 1; g2 < 8; ++g2){ u64 k2 = red[g2][tid]; b = (k2 < b) ? k2 : b; }
        int c = (int)(b & 0xffffffffu);
        asg[run*NPTS + qt*128 + tid] = c;
        atomicAdd(&cnt[run*KCL + c], 1);
    }
}

// ---- kmeans partial sums: 8-deep load batching ----
__global__ __launch_bounds__(256) void k_sums(float* __restrict__ ws){
    int bx = blockIdx.x; int pg = bx & 1, dh = (bx >> 1) & 1, run = bx >> 2;
    int tid = threadIdx.x;
    __shared__ float sm[KCL*256];
    __shared__ int a[512];
    const int* asg = (const int*)(ws + O_ASG);
    for (int idx = tid; idx < 512; idx += 256) a[idx] = asg[run*NPTS + pg*512 + idx];
    for (int idx = tid; idx < KCL*256; idx += 256) sm[idx] = 0.f;
    __syncthreads();
    const float* pT = ws + O_PTST + ((size_t)run*NPTS + pg*512)*DIMD + dh*256 + tid;
    for (int p = 0; p < 512; p += 8){
        float v[8];
        #pragma unroll
        for (int u = 0; u < 8; ++u) v[u] = pT[(size_t)(p+u)*DIMD];
        #pragma unroll
        for (int u = 0; u < 8; ++u) sm[a[p+u]*256 + tid] += v[u];
    }
    __syncthreads();
    size_t psx = pg ? O_PS1 : O_PS0;
    for (int c = 0; c < KCL; ++c)
        ws[psx + ((size_t)run*KCL + c)*DIMD + dh*256 + tid] = sm[c*256 + tid];
}

// ---- kmeans center update + sqc + zero cnt (deterministic: ps0+ps1) ----
__global__ __launch_bounds__(256) void k_newc(float* __restrict__ ws){
    int run = blockIdx.x, tid = threadIdx.x;
    __shared__ float sm2[KCL*65];
    __shared__ int cl[KCL];
    int* cnt = (int*)(ws + O_CNT);
    if (tid < KCL) cl[tid] = cnt[run*KCL + tid];
    __syncthreads();
    if (tid < KCL) cnt[run*KCL + tid] = 0;
    float sqa = 0.f;
    for (int dc = 0; dc < 8; ++dc){
        for (int idx = tid; idx < KCL*64; idx += 256){
            int c = idx >> 6, dl = idx & 63;
            size_t o = ((size_t)run*KCL + c)*DIMD + dc*64 + dl;
            sm2[c*65 + dl] = ws[O_PS0 + o] + ws[O_PS1 + o];
        }
        __syncthreads();
        for (int idx = tid; idx < KCL*64; idx += 256){
            int dl = idx >> 6, c = idx & 63, d = dc*64 + dl;
            size_t gi = O_CTG + (size_t)run*DIMD*KCL + d*KCL + c;
            float old = ws[gi];
            int cc = cl[c];
            float nv = (cc > 0) ? sm2[c*65 + dl] / (float)cc : old;
            ws[gi] = nv;
            sm2[c*65 + dl] = nv;
        }
        __syncthreads();
        if (tid < KCL){
            for (int dl = 0; dl < 64; ++dl){ float v = sm2[tid*65 + dl]; sqa = fmaf(v, v, sqa); }
        }
        __syncthreads();
    }
    if (tid < KCL) ws[O_SQC + run*KCL + tid] = sqa;
}

// ---- regroup centers to row-major: target -> CTN [n][256c][512d]; source -> CS [n][4i][64k][512d] ----
__global__ __launch_bounds__(256) void k_ctn(float* __restrict__ ws){
    int bx = blockIdx.x; int dc = bx & 7, jj = (bx >> 3) & 3, n = (bx >> 5) & 7, st = bx >> 8;
    int run = st ? (jj*8 + n) : (32 + jj*8 + n);
    int tid = threadIdx.x, lane = tid & 63, r4 = tid >> 6;
    __shared__ float t[64*65];
    for (int pass = 0; pass < 16; ++pass){
        int r = pass*4 + r4;
        t[r*65 + lane] = ws[O_CTG + (size_t)run*DIMD*KCL + (dc*64 + r)*KCL + lane];
    }
    __syncthreads();
    size_t dstbase = st ? (O_CS  + ((size_t)(n*4 + jj)*64)*DIMD)
                        : (O_CTN + ((size_t)n*256 + jj*64)*DIMD);
    for (int pass = 0; pass < 16; ++pass){
        int l = pass*4 + r4;
        ws[dstbase + (size_t)l*DIMD + dc*64 + lane] = t[lane*65 + l];
    }
}

// ---- source->target center matching ----
__global__ __launch_bounds__(256) void k_map(float* __restrict__ ws){
    int bx = blockIdx.x; int j = bx & 3, i = (bx >> 2) & 3, n = bx >> 4;
    int run_s = i*8 + n, run_t = 32 + j*8 + n;
    int tid = threadIdx.x, lane = tid & 63;
    int g = __builtin_amdgcn_readfirstlane(tid >> 6);
    const float* cgs = ws + O_CTG + (size_t)run_s*DIMD*KCL + lane;
    const float* cgt = ws + O_CTG + (size_t)run_t*DIMD*KCL + g*16;
    float acc[16] = {};
    for (int d = 0; d < DIMD; ++d){
        float csv = cgs[d*KCL];
        const float4* cp = (const float4*)(cgt + d*KCL);
        float4 c0=cp[0], c1=cp[1], c2=cp[2], c3=cp[3];
        float cv[16] = {c0.x,c0.y,c0.z,c0.w, c1.x,c1.y,c1.z,c1.w,
                        c2.x,c2.y,c2.z,c2.w, c3.x,c3.y,c3.z,c3.w};
        #pragma unroll
        for (int cl = 0; cl < 16; ++cl) acc[cl] = fmaf(csv, cv[cl], acc[cl]);
    }
    float sqs = ws[O_SQC + run_s*KCL + lane];
    const float* sqtp = ws + O_SQC + run_t*KCL + g*16;
    u64 best = dpack(sqs + sqtp[0] - 2.f*acc[0], g*16);
    #pragma unroll
    for (int cl = 1; cl < 16; ++cl){
        u64 k2 = dpack(sqs + sqtp[cl] - 2.f*acc[cl], g*16 + cl);
        best = (k2 < best) ? k2 : best;
    }
    __shared__ u64 red[4][64];
    red[g][lane] = best;
    __syncthreads();
    if (tid < 64){
        u64 b = red[0][tid];
        #pragma unroll
        for (int g2 = 1; g2 < 4; ++g2){ u64 k2 = red[g2][tid]; b = (k2 < b) ? k2 : b; }
        int l = (int)(b & 0xffffffffu);
        int* yv   = (int*)(ws + O_Y);
        int* cnt2 = (int*)(ws + O_CNT2);
        yv[((n*4 + i)*4 + j)*64 + tid] = l;
        atomicAdd(&cnt2[n*256 + j*64 + l], 1);
    }
}

// ---- B matrix: serial gather-accumulate over 256 sources, coalesced rows, no atomics ----
__global__ __launch_bounds__(256) void k_bmat(float* __restrict__ ws){
    int bx = blockIdx.x; int dh = bx & 1, j = (bx >> 1) & 3, n = bx >> 3;
    int tid = threadIdx.x;
    __shared__ float Bacc[KCL*256];   // 64 KB
    __shared__ int yl[256];
    __shared__ int c2[KCL];
    const int* yv   = (const int*)(ws + O_Y);
    const int* cnt2 = (const int*)(ws + O_CNT2);
    { int i = tid >> 6, k = tid & 63; yl[tid] = yv[((n*4 + i)*4 + j)*64 + k]; }
    if (tid < KCL) c2[tid] = cnt2[n*256 + j*64 + tid];
    for (int idx = tid; idx < KCL*256; idx += 256) Bacc[idx] = 0.f;
    __syncthreads();
    const float* cs = ws + O_CS + (size_t)(n*4)*64*DIMD + dh*256 + tid;
    #pragma unroll 4
    for (int s = 0; s < 256; ++s){
        int l = yl[s];
        float v = cs[(size_t)s*DIMD];
        Bacc[l*256 + tid] += v;
    }
    __syncthreads();
    for (int l = 0; l < KCL; ++l){
        int cc = c2[l]; if (cc < 1) cc = 1;
        ws[O_BM + ((size_t)n*256 + j*64 + l)*DIMD + dh*256 + tid] = Bacc[l*256 + tid] / (float)cc;
    }
}

// ---- masked Gram: tiled A·A^T over CTN rows (coalesced, L2-friendly) ----
__global__ __launch_bounds__(256) void k_gram(float* __restrict__ ws){
    int bx = blockIdx.x; int ti = bx & 3, tj = (bx >> 2) & 3, n = bx >> 4;
    int tid = threadIdx.x;
    int tx = tid & 15, ty = tid >> 4;
    const float* A = ws + O_CTN + (size_t)n*256*DIMD;
    __shared__ __align__(16) float Ai[64*65];
    __shared__ __align__(16) float Aj[64*65];
    float acc[4][4] = {};
    for (int kc = 0; kc < 8; ++kc){
        __syncthreads();
        for (int idx = tid; idx < 1024; idx += 256){
            int r = idx >> 4, c4 = idx & 15;
            *(float4*)&Ai[r*65 + c4*4] = *(const float4*)&A[(size_t)(ti*64 + r)*DIMD + kc*64 + c4*4];
            *(float4*)&Aj[r*65 + c4*4] = *(const float4*)&A[(size_t)(tj*64 + r)*DIMD + kc*64 + c4*4];
        }
        __syncthreads();
        #pragma unroll 8
        for (int k = 0; k < 64; ++k){
            float ar[4], br[4];
            #pragma unroll
            for (int a = 0; a < 4; ++a) ar[a] = Ai[(ty*4 + a)*65 + k];
            #pragma unroll
            for (int b = 0; b < 4; ++b) br[b] = Aj[(tx*4 + b)*65 + k];
            #pragma unroll
            for (int a = 0; a < 4; ++a)
                #pragma unroll
                for (int b = 0; b < 4; ++b)
                    acc[a][b] = fmaf(ar[a], br[b], acc[a][b]);
        }
    }
    const int* cnt2 = (const int*)(ws + O_CNT2);
    float* Gp = ws + O_G + (size_t)n*65536;
    #pragma unroll
    for (int a = 0; a < 4; ++a){
        int row = ti*64 + ty*4 + a;
        bool ur = cnt2[n*256 + row] > 0;
        #pragma unroll
        for (int b = 0; b < 4; ++b){
            int col = tj*64 + tx*4 + b;
            bool uc = cnt2[n*256 + col] > 0;
            float v = (ur && uc) ? acc[a][b] : ((row == col) ? 1.f : 0.f);
            Gp[(size_t)row*256 + col] = v;
        }
    }
}

// ---- Cholesky panel: register-lockstep fused diag factor + panel solve (one kb) ----
__global__ __launch_bounds__(256, 1) void k_cholp(float* __restrict__ ws, int kb){
    int n = blockIdx.x, tid = threadIdx.x;
    int lane = tid & 63, wv = tid >> 6;
    float* Gn  = ws + O_G  + (size_t)n*65536;
    float* LTn = ws + O_LT + (size_t)n*65536;
    int c0 = kb*64, r1 = c0 + 64, rem = 256 - r1;

    float dreg[64];
    {
        const float* grow = Gn + (size_t)(c0+lane)*256 + c0;
        #pragma unroll
        for (int j4 = 0; j4 < 16; ++j4){
            float4 v = *(const float4*)&grow[j4*4];
            dreg[j4*4+0]=v.x; dreg[j4*4+1]=v.y; dreg[j4*4+2]=v.z; dreg[j4*4+3]=v.w;
        }
    }
    float preg[64];
    int prow = (wv-1)*64 + lane;
    bool pact = (wv >= 1) && (prow < rem);
    {
        const float* growp = Gn + (size_t)(r1+prow)*256 + c0;
        #pragma unroll
        for (int j4 = 0; j4 < 16; ++j4){
            if (pact){
                float4 v = *(const float4*)&growp[j4*4];
                preg[j4*4+0]=v.x; preg[j4*4+1]=v.y; preg[j4*4+2]=v.z; preg[j4*4+3]=v.w;
            } else {
                preg[j4*4+0]=0.f; preg[j4*4+1]=0.f; preg[j4*4+2]=0.f; preg[j4*4+3]=0.f;
            }
        }
    }
    #pragma unroll
    for (int k = 0; k < 64; ++k){
        float dkk = sqrtf(fmaxf(rdlane(dreg[k], k), 1e-30f));
        float inv = 1.f / dkk;
        dreg[k] = (lane == k) ? dkk : dreg[k]*inv;
        preg[k] *= inv;
        #pragma unroll
        for (int j = k+1; j < 64; ++j){
            float s = rdlane(dreg[k], j);
            dreg[j] = fmaf(-dreg[k], s, dreg[j]);
            preg[j] = fmaf(-preg[k], s, preg[j]);
        }
    }
    if (wv == 0){
        float* grow = Gn + (size_t)(c0+lane)*256 + c0;
        #pragma unroll
        for (int j4 = 0; j4 < 16; ++j4){
            float4 v; v.x=dreg[j4*4+0]; v.y=dreg[j4*4+1]; v.z=dreg[j4*4+2]; v.w=dreg[j4*4+3];
            *(float4*)&grow[j4*4] = v;
        }
    }
    if (pact){
        float* growp = Gn + (size_t)(r1+prow)*256 + c0;
        #pragma unroll
        for (int j4 = 0; j4 < 16; ++j4){
            float4 v; v.x=preg[j4*4+0]; v.y=preg[j4*4+1]; v.z=preg[j4*4+2]; v.w=preg[j4*4+3];
            *(float4*)&growp[j4*4] = v;
        }
        float* ltp = LTn + (size_t)c0*256 + r1 + prow;
        #pragma unroll
        for (int j = 0; j < 64; ++j) ltp[(size_t)j*256] = preg[j];
    }
}

// ---- trailing update for panel kb, wide-parallel: C -= Lp * Lp^T (lower 4x4 tiles) ----
__global__ __launch_bounds__(256) void k_trail(float* __restrict__ ws, int kb){
    int n = blockIdx.y;
    int c0 = kb*64, r1 = c0 + 64, rem = 256 - r1;
    int nt4 = rem >> 2;
    int ntiles = nt4*(nt4+1)/2;
    float* Gn = ws + O_G + (size_t)n*65536;
    for (int t = blockIdx.x*256 + threadIdx.x; t < ntiles; t += gridDim.x*256){
        int ti = (int)((sqrtf(8.f*(float)t + 1.f) - 1.f) * 0.5f);
        while ((ti+1)*(ti+2)/2 <= t) ++ti;
        while (ti*(ti+1)/2 > t) --ti;
        int tj = t - ti*(ti+1)/2;
        int i0 = ti*4, j0 = tj*4;
        const float* Li = Gn + (size_t)(r1+i0)*256 + c0;
        const float* Lj = Gn + (size_t)(r1+j0)*256 + c0;
        float acc[4][4] = {};
        for (int k = 0; k < 64; k += 4){
            float4 ar4[4], br4[4];
            #pragma unroll
            for (int r = 0; r < 4; ++r) ar4[r] = *(const float4*)&Li[(size_t)r*256 + k];
            #pragma unroll
            for (int s = 0; s < 4; ++s) br4[s] = *(const float4*)&Lj[(size_t)s*256 + k];
            #pragma unroll
            for (int q = 0; q < 4; ++q){
                float aq[4] = { q==0?ar4[0].x:q==1?ar4[0].y:q==2?ar4[0].z:ar4[0].w,
                                q==0?ar4[1].x:q==1?ar4[1].y:q==2?ar4[1].z:ar4[1].w,
                                q==0?ar4[2].x:q==1?ar4[2].y:q==2?ar4[2].z:ar4[2].w,
                                q==0?ar4[3].x:q==1?ar4[3].y:q==2?ar4[3].z:ar4[3].w };
                float bq[4] = { q==0?br4[0].x:q==1?br4[0].y:q==2?br4[0].z:br4[0].w,
                                q==0?br4[1].x:q==1?br4[1].y:q==2?br4[1].z:br4[1].w,
                                q==0?br4[2].x:q==1?br4[2].y:q==2?br4[2].z:br4[2].w,
                                q==0?br4[3].x:q==1?br4[3].y:q==2?br4[3].z:br4[3].w };
                #pragma unroll
                for (int r = 0; r < 4; ++r)
                    #pragma unroll
                    for (int s = 0; s < 4; ++s)
                        acc[r][s] = fmaf(aq[r], bq[s], acc[r][s]);
            }
        }
        #pragma unroll
        for (int r = 0; r < 4; ++r){
            float* grow = Gn + (size_t)(r1+i0+r)*256 + r1 + j0;
            #pragma unroll
            for (int s = 0; s < 4; ++s) grow[s] -= acc[r][s];
        }
    }
}

// ---- diag-block inverses: W_i = inv(L_ii), column-parallel per lane ----
__global__ __launch_bounds__(256, 1) void k_dinv(float* __restrict__ ws){
    int n = blockIdx.x, tid = threadIdx.x;
    int lane = tid & 63, kb = tid >> 6;
    const float* Gn = ws + O_G + (size_t)n*65536;
    __shared__ __align__(16) float DlT[4][64*65];   // DlT[kb][k*65+i] = L[i][k]
    for (int idx = lane; idx < 1024; idx += 64){
        int r = idx >> 4, c4 = idx & 15;
        float4 v = *(const float4*)&Gn[(size_t)(kb*64 + r)*256 + kb*64 + c4*4];
        DlT[kb][(c4*4+0)*65 + r] = v.x;
        DlT[kb][(c4*4+1)*65 + r] = v.y;
        DlT[kb][(c4*4+2)*65 + r] = v.z;
        DlT[kb][(c4*4+3)*65 + r] = v.w;
    }
    __syncthreads();
    float x[64];
    #pragma unroll
    for (int i = 0; i < 64; ++i) x[i] = (i == lane) ? 1.f : 0.f;
    const float* Dk = DlT[kb];
    #pragma unroll
    for (int k = 0; k < 64; ++k){
        float invd = 1.f / Dk[k*65 + k];
        x[k] *= invd;
        #pragma unroll
        for (int i = k+1; i < 64; ++i)
            x[i] = fmaf(-Dk[k*65 + i], x[k], x[i]);
    }
    float* Wg  = ws + O_W  + ((size_t)n*4 + kb)*4096;
    float* WTg = ws + O_WT + ((size_t)n*4 + kb)*4096;
    #pragma unroll
    for (int r = 0; r < 64; ++r) Wg[r*64 + lane] = x[r];
    #pragma unroll
    for (int r4 = 0; r4 < 16; ++r4){
        float4 v; v.x=x[r4*4+0]; v.y=x[r4*4+1]; v.z=x[r4*4+2]; v.w=x[r4*4+3];
        *(float4*)&WTg[lane*64 + r4*4] = v;
    }
}

// ---- triangular solves as block GEMMs, 32-col blocks for 2/CU occupancy ----
// grid (8 n, 16 cg), 128 threads: tx = col-tile (8x4=32 cols), ty = row-tile (16x4=64 rows).
__global__ __launch_bounds__(128, 2) void k_solve(float* __restrict__ ws){
    int n = blockIdx.x, cg = blockIdx.y;
    int tid = threadIdx.x;
    int tx = tid & 7, ty = tid >> 3;
    const float* Gn  = ws + O_G  + (size_t)n*65536;
    const float* LTn = ws + O_LT + (size_t)n*65536;
    const float* Ct  = ws + O_CTN + (size_t)n*256*DIMD + (size_t)cg*32;
    const float* Wg  = ws + O_W  + (size_t)n*4*4096;
    const float* WTg = ws + O_WT + (size_t)n*4*4096;
    float* Zb = ws + O_ZB + (size_t)n*256*DIMD + (size_t)cg*32;

    __shared__ __align__(16) float YL[4][64*33];
    __shared__ __align__(16) float At[64*64];
    __shared__ __align__(16) float RL[64*33];

    float acc[4][4];
    for (int bi = 0; bi < 4; ++bi){
        #pragma unroll
        for (int a = 0; a < 4; ++a){
            float4 v = *(const float4*)&Ct[(size_t)(bi*64 + ty*4 + a)*DIMD + tx*4];
            acc[a][0]=v.x; acc[a][1]=v.y; acc[a][2]=v.z; acc[a][3]=v.w;
        }
        for (int j = 0; j < bi; ++j){
            __syncthreads();
            for (int idx = tid; idx < 1024; idx += 128){
                int k = idx >> 4, r4 = idx & 15;
                float4 v = *(const float4*)&LTn[(size_t)(j*64 + k)*256 + bi*64 + r4*4];
                *(float4*)&At[k*64 + r4*4] = v;
            }
            __syncthreads();
            const float* Yj = YL[j];
            #pragma unroll 8
            for (int k = 0; k < 64; ++k){
                float4 av = *(const float4*)&At[k*64 + ty*4];
                float4 yv = *(const float4*)&Yj[k*33 + tx*4];
                float ar[4] = {av.x,av.y,av.z,av.w};
                float yr[4] = {yv.x,yv.y,yv.z,yv.w};
                #pragma unroll
                for (int a = 0; a < 4; ++a)
                    #pragma unroll
                    for (int b = 0; b < 4; ++b)
                        acc[a][b] = fmaf(-ar[a], yr[b], acc[a][b]);
            }
        }
        __syncthreads();
        #pragma unroll
        for (int a = 0; a < 4; ++a){
            float4 v; v.x=acc[a][0]; v.y=acc[a][1]; v.z=acc[a][2]; v.w=acc[a][3];
            *(float4*)&RL[(ty*4 + a)*33 + tx*4] = v;
        }
        for (int idx = tid; idx < 1024; idx += 128){
            int k = idx >> 4, r4 = idx & 15;
            float4 v = *(const float4*)&WTg[(size_t)bi*4096 + k*64 + r4*4];
            *(float4*)&At[k*64 + r4*4] = v;
        }
        __syncthreads();
        float out[4][4] = {};
        #pragma unroll 8
        for (int k = 0; k < 64; ++k){
            float4 av = *(const float4*)&At[k*64 + ty*4];
            float4 rv = *(const float4*)&RL[k*33 + tx*4];
            float ar[4] = {av.x,av.y,av.z,av.w};
            float rr[4] = {rv.x,rv.y,rv.z,rv.w};
            #pragma unroll
            for (int a = 0; a < 4; ++a)
                #pragma unroll
                for (int b = 0; b < 4; ++b)
                    out[a][b] = fmaf(ar[a], rr[b], out[a][b]);
        }
        float* Yi = YL[bi];
        #pragma unroll
        for (int a = 0; a < 4; ++a){
            float4 v; v.x=out[a][0]; v.y=out[a][1]; v.z=out[a][2]; v.w=out[a][3];
            *(float4*)&Yi[(ty*4 + a)*33 + tx*4] = v;
        }
    }
    for (int bi = 3; bi >= 0; --bi){
        __syncthreads();
        #pragma unroll
        for (int a = 0; a < 4; ++a){
            float4 v = *(const float4*)&YL[bi][(ty*4 + a)*33 + tx*4];
            acc[a][0]=v.x; acc[a][1]=v.y; acc[a][2]=v.z; acc[a][3]=v.w;
        }
        for (int j = bi+1; j < 4; ++j){
            __syncthreads();
            for (int idx = tid; idx < 1024; idx += 128){
                int k = idx >> 4, r4 = idx & 15;
                float4 v = *(const float4*)&Gn[(size_t)(j*64 + k)*256 + bi*64 + r4*4];
                *(float4*)&At[k*64 + r4*4] = v;
            }
            __syncthreads();
            const float* Zj = YL[j];
            #pragma unroll 8
            for (int k = 0; k < 64; ++k){
                float4 av = *(const float4*)&At[k*64 + ty*4];
                float4 zv = *(const float4*)&Zj[k*33 + tx*4];
                float ar[4] = {av.x,av.y,av.z,av.w};
                float zr[4] = {zv.x,zv.y,zv.z,zv.w};
                #pragma unroll
                for (int a = 0; a < 4; ++a)
                    #pragma unroll
                    for (int b = 0; b < 4; ++b)
                        acc[a][b] = fmaf(-ar[a], zr[b], acc[a][b]);
            }
        }
        __syncthreads();
        #pragma unroll
        for (int a = 0; a < 4; ++a){
            float4 v; v.x=acc[a][0]; v.y=acc[a][1]; v.z=acc[a][2]; v.w=acc[a][3];
            *(float4*)&RL[(ty*4 + a)*33 + tx*4] = v;
        }
        for (int idx = tid; idx < 1024; idx += 128){
            int k = idx >> 4, r4 = idx & 15;
            float4 v = *(const float4*)&Wg[(size_t)bi*4096 + k*64 + r4*4];
            *(float4*)&At[k*64 + r4*4] = v;
        }
        __syncthreads();
        float out[4][4] = {};
        #pragma unroll 8
        for (int k = 0; k < 64; ++k){
            float4 av = *(const float4*)&At[k*64 + ty*4];
            float4 rv = *(const float4*)&RL[k*33 + tx*4];
            float ar[4] = {av.x,av.y,av.z,av.w};
            float rr[4] = {rv.x,rv.y,rv.z,rv.w};
            #pragma unroll
            for (int a = 0; a < 4; ++a)
                #pragma unroll
                for (int b = 0; b < 4; ++b)
                    out[a][b] = fmaf(ar[a], rr[b], out[a][b]);
        }
        float* Zi = YL[bi];
        #pragma unroll
        for (int a = 0; a < 4; ++a){
            float4 v; v.x=out[a][0]; v.y=out[a][1]; v.z=out[a][2]; v.w=out[a][3];
            *(float4*)&Zi[(ty*4 + a)*33 + tx*4] = v;
            *(float4*)&Zb[(size_t)(bi*64 + ty*4 + a)*DIMD + tx*4] = v;
        }
    }
}

// ---- final GEMM: trans[d][e] = sum_c Bm[c][d] * Z[c][e] ----
__global__ __launch_bounds__(256) void k_gemmE(const float* __restrict__ ws, float* __restrict__ out){
    int bx = blockIdx.x; int et = bx & 7, dt = (bx >> 3) & 7, n = bx >> 6;
    int tid = threadIdx.x;
    __shared__ float Bl[256*64];
    __shared__ float Zl[256*64];
    const float* Bm = ws + O_BM + (size_t)n*256*DIMD;
    const float* Zb = ws + O_ZB + (size_t)n*256*DIMD;
    for (int idx = tid; idx < 16384; idx += 256){
        int c = idx >> 6, dd = idx & 63;
        Bl[idx] = Bm[(size_t)c*DIMD + dt*64 + dd];
        Zl[idx] = Zb[(size_t)c*DIMD + et*64 + dd];
    }
    __syncthreads();
    int td = tid & 15, te = tid >> 4;
    float acc[4][4] = {};
    for (int c = 0; c < 256; ++c){
        float4 bv = *(const float4*)&Bl[c*64 + td*4];
        float4 zv = *(const float4*)&Zl[c*64 + te*4];
        float b4[4] = {bv.x, bv.y, bv.z, bv.w};
        float z4[4] = {zv.x, zv.y, zv.z, zv.w};
        #pragma unroll
        for (int r = 0; r < 4; ++r)
            #pragma unroll
            for (int s = 0; s < 4; ++s) acc[r][s] = fmaf(b4[r], z4[s], acc[r][s]);
    }
    float* ob = out + (size_t)n*262144 + (size_t)(dt*64 + td*4)*DIMD + et*64 + te*4;
    #pragma unroll
    for (int r = 0; r < 4; ++r){
        float4 o; o.x = acc[r][0]; o.y = acc[r][1]; o.z = acc[r][2]; o.w = acc[r][3];
        *(float4*)&ob[(size_t)r*DIMD] = o;
    }
}

extern "C" void kernel_launch(void* const* d_in, const int* in_sizes, int n_in,
                              void* d_out, int out_size, void* d_ws, size_t ws_size,
                              hipStream_t stream){
    const float* src = (const float*)d_in[0];
    const float* tgt = (const float*)d_in[1];
    float* ws  = (float*)d_ws;
    float* out = (float*)d_out;

    k_init<<<256, 256, 0, stream>>>(src, tgt, ws);
    k_ptsT<<<8192, 256, 0, stream>>>(src, tgt, ws);

    for (int it = 0; it < KMIT; ++it){
        k_assign<<<512, 512, 0, stream>>>(src, tgt,
                                          ws + O_CTG, ws + O_SQC, ws + O_SQP,
                                          (int*)(ws + O_ASG), (int*)(ws + O_CNT));
        k_sums<<<256, 256, 0, stream>>>(ws);
        k_newc<<<64, 256, 0, stream>>>(ws);
    }

    hipMemsetAsync((char*)d_ws + O_CNT2*4, 0, 8*256*4, stream);
    k_ctn<<<512, 256, 0, stream>>>(ws);
    k_map<<<128, 256, 0, stream>>>(ws);
    k_bmat<<<64, 256, 0, stream>>>(ws);
    k_gram<<<128, 256, 0, stream>>>(ws);
    for (int kb = 0; kb < 4; ++kb){
        k_cholp<<<8, 256, 0, stream>>>(ws, kb);
        if (kb < 3) k_trail<<<dim3(8, 8), 256, 0, stream>>>(ws, kb);
    }
    k_dinv<<<8, 256, 0, stream>>>(ws);
    k_solve<<<dim3(8, 16), 128, 0, stream>>>(ws);
    k_gemmE<<<512, 256, 0, stream>>>(ws, out);
}

// Round 19
// 2164.354 us; speedup vs baseline: 1.2006x; 1.0089x over previous
//
#include <hip/hip_runtime.h>

typedef unsigned int u32;
typedef unsigned long long u64;

#define NPTS  1024
#define DIMD  512
#define KCL   64
#define KMIT  10

// ---- workspace layout (element offsets, all 4-byte elems) ----
constexpr size_t O_CTG  = 0;                        // [64 runs][512 d][64 c]
constexpr size_t O_SUMS = O_CTG  + 64ull*512*64;    // [64][64 c][512 d] (reused: PS0, then CS)
constexpr size_t O_CNT  = O_SUMS + 64ull*64*512;    // [64][64] int
constexpr size_t O_SQC  = O_CNT  + 64ull*64;        // [64][64]
constexpr size_t O_SQP  = O_SQC  + 64ull*64;        // [64][1024]
constexpr size_t O_ASG  = O_SQP  + 64ull*1024;      // [64][1024] int
constexpr size_t O_CTN  = O_ASG  + 64ull*1024;      // [8 n][256 c][512 d]
constexpr size_t O_Y    = O_CTN  + 8ull*256*512;    // [8][4][4][64] int
constexpr size_t O_CNT2 = O_Y    + 8ull*4*4*64;     // [8][256] int
constexpr size_t O_BM   = O_CNT2 + 8ull*256;        // [8][256 c][512 d]
constexpr size_t O_G    = O_BM   + 8ull*256*512;    // [8][256][256]
constexpr size_t O_LT   = O_G    + 8ull*256*256;    // [8][256][256]  LT[a][b]=L[b][a]
constexpr size_t O_YB   = O_LT   + 8ull*256*256;    // [8][256][512] (reused: W/WT)
constexpr size_t O_ZB   = O_YB   + 8ull*256*512;    // [8][256][512]
constexpr size_t O_PTST = O_ZB   + 8ull*256*512;    // [64][1024 p][512 d]

// partial sums for kmeans (loop-phase only).
constexpr size_t O_PS0 = O_SUMS;                    // [64][64 c][512 d]
constexpr size_t O_PS1 = O_CTN;                     // [64][64 c][512 d]
static_assert(O_PS1 + 64ull*64*512 <= O_G, "PS1 overlay must fit before O_G");

// post-loop overlays:
constexpr size_t O_CS = O_SUMS;                     // [8 n][4 i][64 k][512 d] source centers rows
constexpr size_t O_W  = O_YB;                       // [8][4][64 r][64 k]  W = inv(L_ii)
constexpr size_t O_WT = O_YB + 8ull*4*64*64;        // [8][4][64 k][64 r]  W^T

__device__ __forceinline__ const float* run_base(const float* s, const float* t, int run){
    const float* b = (run < 32) ? s : t;
    return b + (size_t)(run & 31) * (DIMD * NPTS);
}
// monotonic pack of (d2, idx): min picks smallest d2, ties -> smallest idx (matches jnp.argmin)
__device__ __forceinline__ u64 dpack(float d2, int c){
    u32 u = __float_as_uint(d2);
    u = (u & 0x80000000u) ? ~u : (u | 0x80000000u);
    return ((u64)u << 32) | (u32)c;
}
__device__ __forceinline__ float rdlane(float v, int l){
    return __uint_as_float(__builtin_amdgcn_readlane(__float_as_uint(v), l));
}

// ---- init: sqp (per-point |p|^2), initial centers (first 64 pts), sqc, zero cnt ----
__global__ __launch_bounds__(256) void k_init(const float* __restrict__ src, const float* __restrict__ tgt,
                                              float* __restrict__ ws){
    int bx = blockIdx.x; int run = bx >> 2, q = bx & 3;
    int tid = threadIdx.x;
    const float* base = run_base(src, tgt, run);
    int p = q*256 + tid;
    float acc = 0.f;
    for (int d = 0; d < DIMD; ++d){
        float v = base[(size_t)d*NPTS + p];
        acc = fmaf(v, v, acc);
    }
    ws[O_SQP + run*NPTS + p] = acc;
    if (q == 0){
        if (tid < KCL) ws[O_SQC + run*KCL + tid] = acc;
        if (tid < KCL) ((int*)(ws + O_CNT))[run*KCL + tid] = 0;
        for (int idx = tid; idx < DIMD*KCL; idx += 256){
            int d = idx >> 6, c = idx & 63;
            ws[O_CTG + (size_t)run*DIMD*KCL + idx] = base[(size_t)d*NPTS + c];
        }
    }
}

// ---- build transposed points copy [run][p][d] for deterministic sums ----
__global__ __launch_bounds__(256) void k_ptsT(const float* __restrict__ src, const float* __restrict__ tgt,
                                              float* __restrict__ ws){
    int bx = blockIdx.x; int dt = bx & 7, pt = (bx >> 3) & 15, run = bx >> 7;
    int tid = threadIdx.x, lane = tid & 63, r4 = tid >> 6;
    const float* base = run_base(src, tgt, run);
    __shared__ float t[64*65];
    for (int pass = 0; pass < 16; ++pass){
        int r = pass*4 + r4;
        t[r*65 + lane] = base[(size_t)(dt*64 + r)*NPTS + pt*64 + lane];
    }
    __syncthreads();
    for (int pass = 0; pass < 16; ++pass){
        int p = pass*4 + r4;
        ws[O_PTST + ((size_t)run*NPTS + pt*64 + p)*DIMD + dt*64 + lane] = t[lane*65 + p];
    }
}

// ---- kmeans assignment: 512 blocks x 512 threads (8 waves, wave g owns 8 centers) ----
__global__ __launch_bounds__(512, 2) void k_assign(const float* __restrict__ src, const float* __restrict__ tgt,
                                                   const float* __restrict__ ctr, const float* __restrict__ sqc,
                                                   const float* __restrict__ sqp,
                                                   int* __restrict__ asg, int* __restrict__ cnt){
    int bxx = blockIdx.x;                    // 0..511
    int run = bxx >> 3, qt = bxx & 7;
    int tid = threadIdx.x, lane = tid & 63;
    int g = __builtin_amdgcn_readfirstlane(tid >> 6);   // wave 0..7
    int c0 = g*8;                            // this wave's 8 centers
    const float* base = run_base(src, tgt, run);
    const float* cg = ctr + (size_t)run*DIMD*KCL + c0;
    int p0 = qt*128 + 2*lane;                // points p0, p0+1
    float acc[2][8] = {};
    __shared__ u64 red[8][128];

#define LOADP(P, DB) { \
    _Pragma("unroll") \
    for (int u = 0; u < 8; ++u) \
        P[u] = *(const float2*)&base[(size_t)((DB)*8 + u)*NPTS + p0]; }

#define COMPUTE(P, DB) { \
    _Pragma("unroll") \
    for (int u = 0; u < 8; ++u){ \
        const float4* cp = (const float4*)(cg + (size_t)((DB)*8 + u)*KCL); \
        float4 c0v = cp[0], c1v = cp[1]; \
        float cv[8] = {c0v.x,c0v.y,c0v.z,c0v.w, c1v.x,c1v.y,c1v.z,c1v.w}; \
        _Pragma("unroll") \
        for (int cl = 0; cl < 8; ++cl){ \
            acc[0][cl] = fmaf(P[u].x, cv[cl], acc[0][cl]); \
            acc[1][cl] = fmaf(P[u].y, cv[cl], acc[1][cl]); \
        } \
    } }

    float2 pa[8], pb[8];
    LOADP(pa, 0);
    for (int db = 0; db < 64; db += 2){
        if (db + 1 < 64) LOADP(pb, db + 1);
        COMPUTE(pa, db);
        if (db + 2 < 64) LOADP(pa, db + 2);
        COMPUTE(pb, db + 1);
    }
#undef LOADP
#undef COMPUTE

    const float* sqcg = sqc + run*KCL + c0;
    float sq[8];
    #pragma unroll
    for (int q = 0; q < 8; ++q) sq[q] = sqcg[q];
    float2 sq2 = *(const float2*)&sqp[run*NPTS + p0];
    #pragma unroll
    for (int s = 0; s < 2; ++s){
        float sqpv = s ? sq2.y : sq2.x;
        u64 best = dpack(sqpv + sq[0] - 2.f*acc[s][0], c0);
        #pragma unroll
        for (int cl = 1; cl < 8; ++cl){
            u64 k2 = dpack(sqpv + sq[cl] - 2.f*acc[s][cl], c0 + cl);
            best = (k2 < best) ? k2 : best;
        }
        red[g][2*lane + s] = best;
    }
    __syncthreads();
    if (tid < 128){
        u64 b = red[0][tid];
        #pragma unroll
        for (int g2 = 1; g2 < 8; ++g2){ u64 k2 = red[g2][tid]; b = (k2 < b) ? k2 : b; }
        int c = (int)(b & 0xffffffffu);
        asg[run*NPTS + qt*128 + tid] = c;
        atomicAdd(&cnt[run*KCL + c], 1);
    }
}

// ---- kmeans partial sums: 8-deep load batching ----
__global__ __launch_bounds__(256) void k_sums(float* __restrict__ ws){
    int bx = blockIdx.x; int pg = bx & 1, dh = (bx >> 1) & 1, run = bx >> 2;
    int tid = threadIdx.x;
    __shared__ float sm[KCL*256];
    __shared__ int a[512];
    const int* asg = (const int*)(ws + O_ASG);
    for (int idx = tid; idx < 512; idx += 256) a[idx] = asg[run*NPTS + pg*512 + idx];
    for (int idx = tid; idx < KCL*256; idx += 256) sm[idx] = 0.f;
    __syncthreads();
    const float* pT = ws + O_PTST + ((size_t)run*NPTS + pg*512)*DIMD + dh*256 + tid;
    for (int p = 0; p < 512; p += 8){
        float v[8];
        #pragma unroll
        for (int u = 0; u < 8; ++u) v[u] = pT[(size_t)(p+u)*DIMD];
        #pragma unroll
        for (int u = 0; u < 8; ++u) sm[a[p+u]*256 + tid] += v[u];
    }
    __syncthreads();
    size_t psx = pg ? O_PS1 : O_PS0;
    for (int c = 0; c < KCL; ++c)
        ws[psx + ((size_t)run*KCL + c)*DIMD + dh*256 + tid] = sm[c*256 + tid];
}

// ---- kmeans center update + sqc + zero cnt (deterministic: ps0+ps1) ----
__global__ __launch_bounds__(256) void k_newc(float* __restrict__ ws){
    int run = blockIdx.x, tid = threadIdx.x;
    __shared__ float sm2[KCL*65];
    __shared__ int cl[KCL];
    int* cnt = (int*)(ws + O_CNT);
    if (tid < KCL) cl[tid] = cnt[run*KCL + tid];
    __syncthreads();
    if (tid < KCL) cnt[run*KCL + tid] = 0;
    float sqa = 0.f;
    for (int dc = 0; dc < 8; ++dc){
        for (int idx = tid; idx < KCL*64; idx += 256){
            int c = idx >> 6, dl = idx & 63;
            size_t o = ((size_t)run*KCL + c)*DIMD + dc*64 + dl;
            sm2[c*65 + dl] = ws[O_PS0 + o] + ws[O_PS1 + o];
        }
        __syncthreads();
        for (int idx = tid; idx < KCL*64; idx += 256){
            int dl = idx >> 6, c = idx & 63, d = dc*64 + dl;
            size_t gi = O_CTG + (size_t)run*DIMD*KCL + d*KCL + c;
            float old = ws[gi];
            int cc = cl[c];
            float nv = (cc > 0) ? sm2[c*65 + dl] / (float)cc : old;
            ws[gi] = nv;
            sm2[c*65 + dl] = nv;
        }
        __syncthreads();
        if (tid < KCL){
            for (int dl = 0; dl < 64; ++dl){ float v = sm2[tid*65 + dl]; sqa = fmaf(v, v, sqa); }
        }
        __syncthreads();
    }
    if (tid < KCL) ws[O_SQC + run*KCL + tid] = sqa;
}

// ---- regroup centers to row-major: target -> CTN [n][256c][512d]; source -> CS [n][4i][64k][512d] ----
__global__ __launch_bounds__(256) void k_ctn(float* __restrict__ ws){
    int bx = blockIdx.x; int dc = bx & 7, jj = (bx >> 3) & 3, n = (bx >> 5) & 7, st = bx >> 8;
    int run = st ? (jj*8 + n) : (32 + jj*8 + n);
    int tid = threadIdx.x, lane = tid & 63, r4 = tid >> 6;
    __shared__ float t[64*65];
    for (int pass = 0; pass < 16; ++pass){
        int r = pass*4 + r4;
        t[r*65 + lane] = ws[O_CTG + (size_t)run*DIMD*KCL + (dc*64 + r)*KCL + lane];
    }
    __syncthreads();
    size_t dstbase = st ? (O_CS  + ((size_t)(n*4 + jj)*64)*DIMD)
                        : (O_CTN + ((size_t)n*256 + jj*64)*DIMD);
    for (int pass = 0; pass < 16; ++pass){
        int l = pass*4 + r4;
        ws[dstbase + (size_t)l*DIMD + dc*64 + lane] = t[lane*65 + l];
    }
}

// ---- source->target center matching ----
__global__ __launch_bounds__(256) void k_map(float* __restrict__ ws){
    int bx = blockIdx.x; int j = bx & 3, i = (bx >> 2) & 3, n = bx >> 4;
    int run_s = i*8 + n, run_t = 32 + j*8 + n;
    int tid = threadIdx.x, lane = tid & 63;
    int g = __builtin_amdgcn_readfirstlane(tid >> 6);
    const float* cgs = ws + O_CTG + (size_t)run_s*DIMD*KCL + lane;
    const float* cgt = ws + O_CTG + (size_t)run_t*DIMD*KCL + g*16;
    float acc[16] = {};
    for (int d = 0; d < DIMD; ++d){
        float csv = cgs[d*KCL];
        const float4* cp = (const float4*)(cgt + d*KCL);
        float4 c0=cp[0], c1=cp[1], c2=cp[2], c3=cp[3];
        float cv[16] = {c0.x,c0.y,c0.z,c0.w, c1.x,c1.y,c1.z,c1.w,
                        c2.x,c2.y,c2.z,c2.w, c3.x,c3.y,c3.z,c3.w};
        #pragma unroll
        for (int cl = 0; cl < 16; ++cl) acc[cl] = fmaf(csv, cv[cl], acc[cl]);
    }
    float sqs = ws[O_SQC + run_s*KCL + lane];
    const float* sqtp = ws + O_SQC + run_t*KCL + g*16;
    u64 best = dpack(sqs + sqtp[0] - 2.f*acc[0], g*16);
    #pragma unroll
    for (int cl = 1; cl < 16; ++cl){
        u64 k2 = dpack(sqs + sqtp[cl] - 2.f*acc[cl], g*16 + cl);
        best = (k2 < best) ? k2 : best;
    }
    __shared__ u64 red[4][64];
    red[g][lane] = best;
    __syncthreads();
    if (tid < 64){
        u64 b = red[0][tid];
        #pragma unroll
        for (int g2 = 1; g2 < 4; ++g2){ u64 k2 = red[g2][tid]; b = (k2 < b) ? k2 : b; }
        int l = (int)(b & 0xffffffffu);
        int* yv   = (int*)(ws + O_Y);
        int* cnt2 = (int*)(ws + O_CNT2);
        yv[((n*4 + i)*4 + j)*64 + tid] = l;
        atomicAdd(&cnt2[n*256 + j*64 + l], 1);
    }
}

// ---- B matrix: serial gather-accumulate over 256 sources, coalesced rows, no atomics ----
__global__ __launch_bounds__(256) void k_bmat(float* __restrict__ ws){
    int bx = blockIdx.x; int dh = bx & 1, j = (bx >> 1) & 3, n = bx >> 3;
    int tid = threadIdx.x;
    __shared__ float Bacc[KCL*256];   // 64 KB
    __shared__ int yl[256];
    __shared__ int c2[KCL];
    const int* yv   = (const int*)(ws + O_Y);
    const int* cnt2 = (const int*)(ws + O_CNT2);
    { int i = tid >> 6, k = tid & 63; yl[tid] = yv[((n*4 + i)*4 + j)*64 + k]; }
    if (tid < KCL) c2[tid] = cnt2[n*256 + j*64 + tid];
    for (int idx = tid; idx < KCL*256; idx += 256) Bacc[idx] = 0.f;
    __syncthreads();
    const float* cs = ws + O_CS + (size_t)(n*4)*64*DIMD + dh*256 + tid;
    #pragma unroll 4
    for (int s = 0; s < 256; ++s){
        int l = yl[s];
        float v = cs[(size_t)s*DIMD];
        Bacc[l*256 + tid] += v;
    }
    __syncthreads();
    for (int l = 0; l < KCL; ++l){
        int cc = c2[l]; if (cc < 1) cc = 1;
        ws[O_BM + ((size_t)n*256 + j*64 + l)*DIMD + dh*256 + tid] = Bacc[l*256 + tid] / (float)cc;
    }
}

// ---- masked Gram: tiled A·A^T over CTN rows (coalesced, L2-friendly) ----
__global__ __launch_bounds__(256) void k_gram(float* __restrict__ ws){
    int bx = blockIdx.x; int ti = bx & 3, tj = (bx >> 2) & 3, n = bx >> 4;
    int tid = threadIdx.x;
    int tx = tid & 15, ty = tid >> 4;
    const float* A = ws + O_CTN + (size_t)n*256*DIMD;
    __shared__ __align__(16) float Ai[64*65];
    __shared__ __align__(16) float Aj[64*65];
    float acc[4][4] = {};
    for (int kc = 0; kc < 8; ++kc){
        __syncthreads();
        for (int idx = tid; idx < 1024; idx += 256){
            int r = idx >> 4, c4 = idx & 15;
            *(float4*)&Ai[r*65 + c4*4] = *(const float4*)&A[(size_t)(ti*64 + r)*DIMD + kc*64 + c4*4];
            *(float4*)&Aj[r*65 + c4*4] = *(const float4*)&A[(size_t)(tj*64 + r)*DIMD + kc*64 + c4*4];
        }
        __syncthreads();
        #pragma unroll 8
        for (int k = 0; k < 64; ++k){
            float ar[4], br[4];
            #pragma unroll
            for (int a = 0; a < 4; ++a) ar[a] = Ai[(ty*4 + a)*65 + k];
            #pragma unroll
            for (int b = 0; b < 4; ++b) br[b] = Aj[(tx*4 + b)*65 + k];
            #pragma unroll
            for (int a = 0; a < 4; ++a)
                #pragma unroll
                for (int b = 0; b < 4; ++b)
                    acc[a][b] = fmaf(ar[a], br[b], acc[a][b]);
        }
    }
    const int* cnt2 = (const int*)(ws + O_CNT2);
    float* Gp = ws + O_G + (size_t)n*65536;
    #pragma unroll
    for (int a = 0; a < 4; ++a){
        int row = ti*64 + ty*4 + a;
        bool ur = cnt2[n*256 + row] > 0;
        #pragma unroll
        for (int b = 0; b < 4; ++b){
            int col = tj*64 + tx*4 + b;
            bool uc = cnt2[n*256 + col] > 0;
            float v = (ur && uc) ? acc[a][b] : ((row == col) ? 1.f : 0.f);
            Gp[(size_t)row*256 + col] = v;
        }
    }
}

// ---- Cholesky panel: register-lockstep fused diag factor + panel solve (one kb) ----
__global__ __launch_bounds__(256, 1) void k_cholp(float* __restrict__ ws, int kb){
    int n = blockIdx.x, tid = threadIdx.x;
    int lane = tid & 63, wv = tid >> 6;
    float* Gn  = ws + O_G  + (size_t)n*65536;
    float* LTn = ws + O_LT + (size_t)n*65536;
    int c0 = kb*64, r1 = c0 + 64, rem = 256 - r1;

    float dreg[64];
    {
        const float* grow = Gn + (size_t)(c0+lane)*256 + c0;
        #pragma unroll
        for (int j4 = 0; j4 < 16; ++j4){
            float4 v = *(const float4*)&grow[j4*4];
            dreg[j4*4+0]=v.x; dreg[j4*4+1]=v.y; dreg[j4*4+2]=v.z; dreg[j4*4+3]=v.w;
        }
    }
    float preg[64];
    int prow = (wv-1)*64 + lane;
    bool pact = (wv >= 1) && (prow < rem);
    {
        const float* growp = Gn + (size_t)(r1+prow)*256 + c0;
        #pragma unroll
        for (int j4 = 0; j4 < 16; ++j4){
            if (pact){
                float4 v = *(const float4*)&growp[j4*4];
                preg[j4*4+0]=v.x; preg[j4*4+1]=v.y; preg[j4*4+2]=v.z; preg[j4*4+3]=v.w;
            } else {
                preg[j4*4+0]=0.f; preg[j4*4+1]=0.f; preg[j4*4+2]=0.f; preg[j4*4+3]=0.f;
            }
        }
    }
    #pragma unroll
    for (int k = 0; k < 64; ++k){
        float dkk = sqrtf(fmaxf(rdlane(dreg[k], k), 1e-30f));
        float inv = 1.f / dkk;
        dreg[k] = (lane == k) ? dkk : dreg[k]*inv;
        preg[k] *= inv;
        #pragma unroll
        for (int j = k+1; j < 64; ++j){
            float s = rdlane(dreg[k], j);
            dreg[j] = fmaf(-dreg[k], s, dreg[j]);
            preg[j] = fmaf(-preg[k], s, preg[j]);
        }
    }
    if (wv == 0){
        float* grow = Gn + (size_t)(c0+lane)*256 + c0;
        #pragma unroll
        for (int j4 = 0; j4 < 16; ++j4){
            float4 v; v.x=dreg[j4*4+0]; v.y=dreg[j4*4+1]; v.z=dreg[j4*4+2]; v.w=dreg[j4*4+3];
            *(float4*)&grow[j4*4] = v;
        }
    }
    if (pact){
        float* growp = Gn + (size_t)(r1+prow)*256 + c0;
        #pragma unroll
        for (int j4 = 0; j4 < 16; ++j4){
            float4 v; v.x=preg[j4*4+0]; v.y=preg[j4*4+1]; v.z=preg[j4*4+2]; v.w=preg[j4*4+3];
            *(float4*)&growp[j4*4] = v;
        }
        float* ltp = LTn + (size_t)c0*256 + r1 + prow;
        #pragma unroll
        for (int j = 0; j < 64; ++j) ltp[(size_t)j*256] = preg[j];
    }
}

// ---- trailing update for panel kb, wide-parallel: C -= Lp * Lp^T (lower 4x4 tiles) ----
__global__ __launch_bounds__(256) void k_trail(float* __restrict__ ws, int kb){
    int n = blockIdx.y;
    int c0 = kb*64, r1 = c0 + 64, rem = 256 - r1;
    int nt4 = rem >> 2;
    int ntiles = nt4*(nt4+1)/2;
    float* Gn = ws + O_G + (size_t)n*65536;
    for (int t = blockIdx.x*256 + threadIdx.x; t < ntiles; t += gridDim.x*256){
        int ti = (int)((sqrtf(8.f*(float)t + 1.f) - 1.f) * 0.5f);
        while ((ti+1)*(ti+2)/2 <= t) ++ti;
        while (ti*(ti+1)/2 > t) --ti;
        int tj = t - ti*(ti+1)/2;
        int i0 = ti*4, j0 = tj*4;
        const float* Li = Gn + (size_t)(r1+i0)*256 + c0;
        const float* Lj = Gn + (size_t)(r1+j0)*256 + c0;
        float acc[4][4] = {};
        for (int k = 0; k < 64; k += 4){
            float4 ar4[4], br4[4];
            #pragma unroll
            for (int r = 0; r < 4; ++r) ar4[r] = *(const float4*)&Li[(size_t)r*256 + k];
            #pragma unroll
            for (int s = 0; s < 4; ++s) br4[s] = *(const float4*)&Lj[(size_t)s*256 + k];
            #pragma unroll
            for (int q = 0; q < 4; ++q){
                float aq[4] = { q==0?ar4[0].x:q==1?ar4[0].y:q==2?ar4[0].z:ar4[0].w,
                                q==0?ar4[1].x:q==1?ar4[1].y:q==2?ar4[1].z:ar4[1].w,
                                q==0?ar4[2].x:q==1?ar4[2].y:q==2?ar4[2].z:ar4[2].w,
                                q==0?ar4[3].x:q==1?ar4[3].y:q==2?ar4[3].z:ar4[3].w };
                float bq[4] = { q==0?br4[0].x:q==1?br4[0].y:q==2?br4[0].z:br4[0].w,
                                q==0?br4[1].x:q==1?br4[1].y:q==2?br4[1].z:br4[1].w,
                                q==0?br4[2].x:q==1?br4[2].y:q==2?br4[2].z:br4[2].w,
                                q==0?br4[3].x:q==1?br4[3].y:q==2?br4[3].z:br4[3].w };
                #pragma unroll
                for (int r = 0; r < 4; ++r)
                    #pragma unroll
                    for (int s = 0; s < 4; ++s)
                        acc[r][s] = fmaf(aq[r], bq[s], acc[r][s]);
            }
        }
        #pragma unroll
        for (int r = 0; r < 4; ++r){
            float* grow = Gn + (size_t)(r1+i0+r)*256 + r1 + j0;
            #pragma unroll
            for (int s = 0; s < 4; ++s) grow[s] -= acc[r][s];
        }
    }
}

// ---- diag-block inverses: W_i = inv(L_ii), column-parallel per lane ----
__global__ __launch_bounds__(256, 1) void k_dinv(float* __restrict__ ws){
    int n = blockIdx.x, tid = threadIdx.x;
    int lane = tid & 63, kb = tid >> 6;
    const float* Gn = ws + O_G + (size_t)n*65536;
    __shared__ __align__(16) float DlT[4][64*65];   // DlT[kb][k*65+i] = L[i][k]
    for (int idx = lane; idx < 1024; idx += 64){
        int r = idx >> 4, c4 = idx & 15;
        float4 v = *(const float4*)&Gn[(size_t)(kb*64 + r)*256 + kb*64 + c4*4];
        DlT[kb][(c4*4+0)*65 + r] = v.x;
        DlT[kb][(c4*4+1)*65 + r] = v.y;
        DlT[kb][(c4*4+2)*65 + r] = v.z;
        DlT[kb][(c4*4+3)*65 + r] = v.w;
    }
    __syncthreads();
    float x[64];
    #pragma unroll
    for (int i = 0; i < 64; ++i) x[i] = (i == lane) ? 1.f : 0.f;
    const float* Dk = DlT[kb];
    #pragma unroll
    for (int k = 0; k < 64; ++k){
        float invd = 1.f / Dk[k*65 + k];
        x[k] *= invd;
        #pragma unroll
        for (int i = k+1; i < 64; ++i)
            x[i] = fmaf(-Dk[k*65 + i], x[k], x[i]);
    }
    float* Wg  = ws + O_W  + ((size_t)n*4 + kb)*4096;
    float* WTg = ws + O_WT + ((size_t)n*4 + kb)*4096;
    #pragma unroll
    for (int r = 0; r < 64; ++r) Wg[r*64 + lane] = x[r];
    #pragma unroll
    for (int r4 = 0; r4 < 16; ++r4){
        float4 v; v.x=x[r4*4+0]; v.y=x[r4*4+1]; v.z=x[r4*4+2]; v.w=x[r4*4+3];
        *(float4*)&WTg[lane*64 + r4*4] = v;
    }
}

// ---- triangular solves as block GEMMs, 16-col blocks: 256 blocks (one per CU) ----
// grid (8 n, 32 cg), 64 threads: tx = col-tile (4x4=16 cols), ty = row-tile (16x4=64 rows).
__global__ __launch_bounds__(64, 4) void k_solve(float* __restrict__ ws){
    int n = blockIdx.x, cg = blockIdx.y;
    int tid = threadIdx.x;
    int tx = tid & 3, ty = tid >> 2;
    const float* Gn  = ws + O_G  + (size_t)n*65536;
    const float* LTn = ws + O_LT + (size_t)n*65536;
    const float* Ct  = ws + O_CTN + (size_t)n*256*DIMD + (size_t)cg*16;
    const float* Wg  = ws + O_W  + (size_t)n*4*4096;
    const float* WTg = ws + O_WT + (size_t)n*4*4096;
    float* Zb = ws + O_ZB + (size_t)n*256*DIMD + (size_t)cg*16;

    __shared__ __align__(16) float YL[4][64*20];
    __shared__ __align__(16) float At[64*64];
    __shared__ __align__(16) float RL[64*20];

    float acc[4][4];
    for (int bi = 0; bi < 4; ++bi){
        #pragma unroll
        for (int a = 0; a < 4; ++a){
            float4 v = *(const float4*)&Ct[(size_t)(bi*64 + ty*4 + a)*DIMD + tx*4];
            acc[a][0]=v.x; acc[a][1]=v.y; acc[a][2]=v.z; acc[a][3]=v.w;
        }
        for (int j = 0; j < bi; ++j){
            __syncthreads();
            for (int idx = tid; idx < 1024; idx += 64){
                int k = idx >> 4, r4 = idx & 15;
                float4 v = *(const float4*)&LTn[(size_t)(j*64 + k)*256 + bi*64 + r4*4];
                *(float4*)&At[k*64 + r4*4] = v;
            }
            __syncthreads();
            const float* Yj = YL[j];
            #pragma unroll 8
            for (int k = 0; k < 64; ++k){
                float4 av = *(const float4*)&At[k*64 + ty*4];
                float4 yv = *(const float4*)&Yj[k*20 + tx*4];
                float ar[4] = {av.x,av.y,av.z,av.w};
                float yr[4] = {yv.x,yv.y,yv.z,yv.w};
                #pragma unroll
                for (int a = 0; a < 4; ++a)
                    #pragma unroll
                    for (int b = 0; b < 4; ++b)
                        acc[a][b] = fmaf(-ar[a], yr[b], acc[a][b]);
            }
        }
        __syncthreads();
        #pragma unroll
        for (int a = 0; a < 4; ++a){
            float4 v; v.x=acc[a][0]; v.y=acc[a][1]; v.z=acc[a][2]; v.w=acc[a][3];
            *(float4*)&RL[(ty*4 + a)*20 + tx*4] = v;
        }
        for (int idx = tid; idx < 1024; idx += 64){
            int k = idx >> 4, r4 = idx & 15;
            float4 v = *(const float4*)&WTg[(size_t)bi*4096 + k*64 + r4*4];
            *(float4*)&At[k*64 + r4*4] = v;
        }
        __syncthreads();
        float out[4][4] = {};
        #pragma unroll 8
        for (int k = 0; k < 64; ++k){
            float4 av = *(const float4*)&At[k*64 + ty*4];
            float4 rv = *(const float4*)&RL[k*20 + tx*4];
            float ar[4] = {av.x,av.y,av.z,av.w};
            float rr[4] = {rv.x,rv.y,rv.z,rv.w};
            #pragma unroll
            for (int a = 0; a < 4; ++a)
                #pragma unroll
                for (int b = 0; b < 4; ++b)
                    out[a][b] = fmaf(ar[a], rr[b], out[a][b]);
        }
        float* Yi = YL[bi];
        #pragma unroll
        for (int a = 0; a < 4; ++a){
            float4 v; v.x=out[a][0]; v.y=out[a][1]; v.z=out[a][2]; v.w=out[a][3];
            *(float4*)&Yi[(ty*4 + a)*20 + tx*4] = v;
        }
    }
    for (int bi = 3; bi >= 0; --bi){
        __syncthreads();
        #pragma unroll
        for (int a = 0; a < 4; ++a){
            float4 v = *(const float4*)&YL[bi][(ty*4 + a)*20 + tx*4];
            acc[a][0]=v.x; acc[a][1]=v.y; acc[a][2]=v.z; acc[a][3]=v.w;
        }
        for (int j = bi+1; j < 4; ++j){
            __syncthreads();
            for (int idx = tid; idx < 1024; idx += 64){
                int k = idx >> 4, r4 = idx & 15;
                float4 v = *(const float4*)&Gn[(size_t)(j*64 + k)*256 + bi*64 + r4*4];
                *(float4*)&At[k*64 + r4*4] = v;
            }
            __syncthreads();
            const float* Zj = YL[j];
            #pragma unroll 8
            for (int k = 0; k < 64; ++k){
                float4 av = *(const float4*)&At[k*64 + ty*4];
                float4 zv = *(const float4*)&Zj[k*20 + tx*4];
                float ar[4] = {av.x,av.y,av.z,av.w};
                float zr[4] = {zv.x,zv.y,zv.z,zv.w};
                #pragma unroll
                for (int a = 0; a < 4; ++a)
                    #pragma unroll
                    for (int b = 0; b < 4; ++b)
                        acc[a][b] = fmaf(-ar[a], zr[b], acc[a][b]);
            }
        }
        __syncthreads();
        #pragma unroll
        for (int a = 0; a < 4; ++a){
            float4 v; v.x=acc[a][0]; v.y=acc[a][1]; v.z=acc[a][2]; v.w=acc[a][3];
            *(float4*)&RL[(ty*4 + a)*20 + tx*4] = v;
        }
        for (int idx = tid; idx < 1024; idx += 64){
            int k = idx >> 4, r4 = idx & 15;
            float4 v = *(const float4*)&Wg[(size_t)bi*4096 + k*64 + r4*4];
            *(float4*)&At[k*64 + r4*4] = v;
        }
        __syncthreads();
        float out[4][4] = {};
        #pragma unroll 8
        for (int k = 0; k < 64; ++k){
            float4 av = *(const float4*)&At[k*64 + ty*4];
            float4 rv = *(const float4*)&RL[k*20 + tx*4];
            float ar[4] = {av.x,av.y,av.z,av.w};
            float rr[4] = {rv.x,rv.y,rv.z,rv.w};
            #pragma unroll
            for (int a = 0; a < 4; ++a)
                #pragma unroll
                for (int b = 0; b < 4; ++b)
                    out[a][b] = fmaf(ar[a], rr[b], out[a][b]);
        }
        float* Zi = YL[bi];
        #pragma unroll
        for (int a = 0; a < 4; ++a){
            float4 v; v.x=out[a][0]; v.y=out[a][1]; v.z=out[a][2]; v.w=out[a][3];
            *(float4*)&Zi[(ty*4 + a)*20 + tx*4] = v;
            *(float4*)&Zb[(size_t)(bi*64 + ty*4 + a)*DIMD + tx*4] = v;
        }
    }
}

// ---- final GEMM: trans[d][e] = sum_c Bm[c][d] * Z[c][e]; 64KB LDS (2 blocks/CU) ----
__global__ __launch_bounds__(256) void k_gemmE(const float* __restrict__ ws, float* __restrict__ out){
    int bx = blockIdx.x; int et = bx & 7, dt = (bx >> 3) & 7, n = bx >> 6;
    int tid = threadIdx.x;
    __shared__ float Bl[128*64];
    __shared__ float Zl[128*64];
    const float* Bm = ws + O_BM + (size_t)n*256*DIMD;
    const float* Zb = ws + O_ZB + (size_t)n*256*DIMD;
    int td = tid & 15, te = tid >> 4;
    float acc[4][4] = {};
    for (int half = 0; half < 2; ++half){
        __syncthreads();
        for (int idx = tid; idx < 8192; idx += 256){
            int c = idx >> 6, dd = idx & 63;
            Bl[idx] = Bm[(size_t)(half*128 + c)*DIMD + dt*64 + dd];
            Zl[idx] = Zb[(size_t)(half*128 + c)*DIMD + et*64 + dd];
        }
        __syncthreads();
        for (int c = 0; c < 128; ++c){
            float4 bv = *(const float4*)&Bl[c*64 + td*4];
            float4 zv = *(const float4*)&Zl[c*64 + te*4];
            float b4[4] = {bv.x, bv.y, bv.z, bv.w};
            float z4[4] = {zv.x, zv.y, zv.z, zv.w};
            #pragma unroll
            for (int r = 0; r < 4; ++r)
                #pragma unroll
                for (int s = 0; s < 4; ++s) acc[r][s] = fmaf(b4[r], z4[s], acc[r][s]);
        }
    }
    float* ob = out + (size_t)n*262144 + (size_t)(dt*64 + td*4)*DIMD + et*64 + te*4;
    #pragma unroll
    for (int r = 0; r < 4; ++r){
        float4 o; o.x = acc[r][0]; o.y = acc[r][1]; o.z = acc[r][2]; o.w = acc[r][3];
        *(float4*)&ob[(size_t)r*DIMD] = o;
    }
}

extern "C" void kernel_launch(void* const* d_in, const int* in_sizes, int n_in,
                              void* d_out, int out_size, void* d_ws, size_t ws_size,
                              hipStream_t stream){
    const float* src = (const float*)d_in[0];
    const float* tgt = (const float*)d_in[1];
    float* ws  = (float*)d_ws;
    float* out = (float*)d_out;

    k_init<<<256, 256, 0, stream>>>(src, tgt, ws);
    k_ptsT<<<8192, 256, 0, stream>>>(src, tgt, ws);

    for (int it = 0; it < KMIT; ++it){
        k_assign<<<512, 512, 0, stream>>>(src, tgt,
                                          ws + O_CTG, ws + O_SQC, ws + O_SQP,
                                          (int*)(ws + O_ASG), (int*)(ws + O_CNT));
        k_sums<<<256, 256, 0, stream>>>(ws);
        k_newc<<<64, 256, 0, stream>>>(ws);
    }

    hipMemsetAsync((char*)d_ws + O_CNT2*4, 0, 8*256*4, stream);
    k_ctn<<<512, 256, 0, stream>>>(ws);
    k_map<<<128, 256, 0, stream>>>(ws);
    k_bmat<<<64, 256, 0, stream>>>(ws);
    k_gram<<<128, 256, 0, stream>>>(ws);
    for (int kb = 0; kb < 4; ++kb){
        k_cholp<<<8, 256, 0, stream>>>(ws, kb);
        if (kb < 3) k_trail<<<dim3(8, 8), 256, 0, stream>>>(ws, kb);
    }
    k_dinv<<<8, 256, 0, stream>>>(ws);
    k_solve<<<dim3(8, 32), 64, 0, stream>>>(ws);
    k_gemmE<<<512, 256, 0, stream>>>(ws, out);
}